// Round 16
// baseline (4498.882 us; speedup 1.0000x reference)
//
#include <hip/hip_runtime.h>
#include <math.h>

#define Bb   16
#define Tt   2048
#define Dd   1024
#define NL   4
#define MTOT (Bb * Tt)   // 32768

typedef float f32x4 __attribute__((ext_vector_type(4)));
typedef short bf16x8 __attribute__((ext_vector_type(8)));

// ---------------------------------------------------------------------------
__device__ __forceinline__ unsigned short f2bf_rne(float x) {
    unsigned u = __float_as_uint(x);
    u += 0x7fffu + ((u >> 16) & 1u);
    return (unsigned short)(u >> 16);
}
__device__ __forceinline__ float bf2f(unsigned short h) {
    return __uint_as_float(((unsigned)h) << 16);
}
__device__ __forceinline__ float gelu_tanh(float x) {
    float x3 = x * x * x;
    float u  = 0.7978845608028654f * (x + 0.044715f * x3);
    return 0.5f * x * (1.0f + tanhf(u));
}
// async 16B global -> LDS (HW: wave-uniform LDS base + lane*16)
__device__ __forceinline__ void dma16(const void* g, void* l) {
    __builtin_amdgcn_global_load_lds(
        (const __attribute__((address_space(1))) unsigned int*)g,
        (__attribute__((address_space(3))) unsigned int*)l, 16, 0, 0);
}

// ---------------------------------------------------------------------------
// Split a [1024,1024] fp32 matrix (row-major [k][n]) into bf16 hi/lo with
// k-tiled, slot-swizzled layout (proven R6 B-path):
//   element (k,n): kt=k>>5, sl=(k>>3)&3, e=k&7
//   shorts offset = ((kt*1024+n)*4 + (sl^((n>>1)&3)))*8 + e
// ---------------------------------------------------------------------------
__global__ __launch_bounds__(256)
void split_bt(const float* __restrict__ B, short* __restrict__ ht,
              short* __restrict__ lt)
{
    __shared__ float tile[32][33];
    const int t  = threadIdx.x;
    const int r  = t >> 3;          // 0..31
    const int c  = (t & 7) * 4;     // 0,4,...,28
    const int kb = blockIdx.y * 32; // kt = blockIdx.y
    const int nb = blockIdx.x * 32;
    float4 v = *reinterpret_cast<const float4*>(
        &B[(size_t)(kb + r) * Dd + nb + c]);
    tile[r][c + 0] = v.x; tile[r][c + 1] = v.y;
    tile[r][c + 2] = v.z; tile[r][c + 3] = v.w;
    __syncthreads();
    unsigned h[4], lo[4];
#pragma unroll
    for (int q = 0; q < 4; ++q) {
        float f = tile[c + q][r];           // B[kb+c+q][nb+r]
        unsigned short hh = f2bf_rne(f);
        float rem = f - bf2f(hh);
        h[q]  = hh;
        lo[q] = f2bf_rne(rem);
    }
    uint2 hw, lw;
    hw.x = h[0]  | (h[1]  << 16); hw.y = h[2]  | (h[3]  << 16);
    lw.x = lo[0] | (lo[1] << 16); lw.y = lo[2] | (lo[3] << 16);
    const int n = nb + r;
    const int s = (c >> 3) ^ ((n >> 1) & 3);   // swizzled slot
    size_t off = ((size_t)(blockIdx.y * 1024 + n) * 4 + s) * 8 + (c & 4);
    *reinterpret_cast<uint2*>(&ht[off]) = hw;
    *reinterpret_cast<uint2*>(&lt[off]) = lw;
}

// ---------------------------------------------------------------------------
// 512-thread split-precision GEMM body: tile 128x256, 8 waves (2M x 4N,
// 64x64 each), 16 waves/CU at 2 blocks. Same proven 2-barrier k-loop and
// LDS layouts/swizzle as the champion 256-thread body — only the wave
// decomposition changes (more TLP, same staged bytes).
// MODE 0: C = A@B (+bias); MODE 1: C[t]=Sin[t]+(t%Tt>=m ? A[t-m]@B : 0).
// WSPLIT=1: epilogue also writes C into the split/swizzled B-layout.
// LDS: Ah[0,5120) Al[5120,10240) Bh[10240,18432) Bl[18432,26624) shorts.
// ---------------------------------------------------------------------------
template<int MODE, int WSPLIT>
__device__ __forceinline__ void gemm512_body(
    short* lds, int bx, int by,
    const float* __restrict__ Af,
    const short* __restrict__ Bth, const short* __restrict__ Btl,
    const float* __restrict__ bias,
    const float* __restrict__ Sin,
    float* __restrict__ Cf,
    short* __restrict__ Woh, short* __restrict__ Wol,
    int m)
{
    constexpr int APL = 5120;            // shorts per A plane (128*40)
    constexpr int BB  = 2 * APL;         // B-hi base
    constexpr int BPL = 8192;            // shorts per B plane (256*32)

    const int tid  = threadIdx.x;
    const int lane = tid & 63;
    const int w    = tid >> 6;           // 0..7
    const int n0   = bx * 256;
    const int m0g  = by * 128;
    const int wm0  = (w >> 2) * 64;
    const int wn0  = (w & 3) * 64;
    const int ln   = lane & 15;
    const int ar   = tid >> 2;           // 0..127 (one A row per thread)
    const int ac   = (tid & 3) * 8;      // 0,8,16,24

    // A source row (+mask for MODE 1)
    const int rg = m0g + ar;
    bool avalid = true;
    if (MODE == 1) avalid = ((rg & (Tt - 1)) >= m);
    const size_t arow = (size_t)((MODE == 1 && avalid) ? (rg - m) : rg);

    f32x4 acc[4][4];
#pragma unroll
    for (int i = 0; i < 4; ++i)
#pragma unroll
        for (int j = 0; j < 4; ++j) acc[i][j] = (f32x4){0.f, 0.f, 0.f, 0.f};

    int a_off[4];
#pragma unroll
    for (int i = 0; i < 4; ++i)
        a_off[i] = (wm0 + i * 16 + ln) * 40 + (lane >> 4) * 8;
    const int nlb    = wn0 + ln;
    const int b_off0 = BB + nlb * 32 +
                       (((lane >> 4) ^ ((nlb >> 1) & 3)) << 3);

    for (int kt = 0; kt < 32; ++kt) {
        __syncthreads();   // previous tile's ds_reads complete
        // ---- stage A: 8 fp32 -> hi/lo bf16 -> two int4 ds_writes ----
        {
            const float* p = &Af[arow * Dd + kt * 32 + ac];
            float4 v0 = *reinterpret_cast<const float4*>(p);
            float4 v1 = *reinterpret_cast<const float4*>(p + 4);
            float f[8] = {v0.x, v0.y, v0.z, v0.w, v1.x, v1.y, v1.z, v1.w};
            if (MODE == 1 && !avalid) {
#pragma unroll
                for (int e = 0; e < 8; ++e) f[e] = 0.f;
            }
            unsigned hh[8], ll[8];
#pragma unroll
            for (int e = 0; e < 8; ++e) {
                unsigned short h = f2bf_rne(f[e]);
                hh[e] = h;
                ll[e] = f2bf_rne(f[e] - bf2f(h));
            }
            int4 hw, lw;
            hw.x = (int)(hh[0] | (hh[1] << 16)); hw.y = (int)(hh[2] | (hh[3] << 16));
            hw.z = (int)(hh[4] | (hh[5] << 16)); hw.w = (int)(hh[6] | (hh[7] << 16));
            lw.x = (int)(ll[0] | (ll[1] << 16)); lw.y = (int)(ll[2] | (ll[3] << 16));
            lw.z = (int)(ll[4] | (ll[5] << 16)); lw.w = (int)(ll[6] | (ll[7] << 16));
            *reinterpret_cast<int4*>(&lds[ar * 40 + ac])       = hw;
            *reinterpret_cast<int4*>(&lds[ar * 40 + ac + APL]) = lw;
        }
        // ---- stage B: 2 frags/plane/thread via dma16 (wave-contig dest) ----
#pragma unroll
        for (int q = 0; q < 2; ++q) {
            int f = q * 512 + tid;
            size_t gfo = ((size_t)(kt * 1024 + n0 + (f >> 2)) * 4 + (f & 3)) * 8;
            short* dh = &lds[BB + q * 4096 + w * 512];
            dma16(&Bth[gfo], dh);
            dma16(&Btl[gfo], dh + BPL);
        }
        __syncthreads();   // drains vmcnt (DMA) + lgkm (A writes)
        // ---- compute: 48 MFMA/wave ----
        bf16x8 ah[4], al[4];
#pragma unroll
        for (int i = 0; i < 4; ++i) {
            ah[i] = *reinterpret_cast<const bf16x8*>(&lds[a_off[i]]);
            al[i] = *reinterpret_cast<const bf16x8*>(&lds[a_off[i] + APL]);
        }
#pragma unroll
        for (int j = 0; j < 4; ++j) {
            const bf16x8 bh = *reinterpret_cast<const bf16x8*>(
                &lds[b_off0 + j * 512]);
            const bf16x8 bl = *reinterpret_cast<const bf16x8*>(
                &lds[b_off0 + j * 512 + BPL]);
#pragma unroll
            for (int i = 0; i < 4; ++i) {
                acc[i][j] = __builtin_amdgcn_mfma_f32_16x16x32_bf16(
                    ah[i], bh, acc[i][j], 0, 0, 0);
                acc[i][j] = __builtin_amdgcn_mfma_f32_16x16x32_bf16(
                    ah[i], bl, acc[i][j], 0, 0, 0);
                acc[i][j] = __builtin_amdgcn_mfma_f32_16x16x32_bf16(
                    al[i], bh, acc[i][j], 0, 0, 0);
            }
        }
    }

    // ---- epilogue ----
#pragma unroll
    for (int j = 0; j < 4; ++j) {
        int cl  = wn0 + j * 16 + ln;
        int col = n0 + cl;
        float bj = (MODE == 0 && bias) ? bias[col] : 0.f;
#pragma unroll
        for (int i = 0; i < 4; ++i) {
            int rbase = m0g + wm0 + i * 16 + (lane >> 4) * 4;
            float vv[4];
#pragma unroll
            for (int e = 0; e < 4; ++e) {
                size_t off = (size_t)(rbase + e) * Dd + col;
                float v = acc[i][j][e] + bj;
                if (MODE == 1) v += Sin[off];
                Cf[off] = v;
                vv[e] = v;
            }
            if (WSPLIT) {
                unsigned short h0 = f2bf_rne(vv[0]), h1 = f2bf_rne(vv[1]),
                               h2 = f2bf_rne(vv[2]), h3 = f2bf_rne(vv[3]);
                unsigned short l0 = f2bf_rne(vv[0] - bf2f(h0)),
                               l1 = f2bf_rne(vv[1] - bf2f(h1)),
                               l2 = f2bf_rne(vv[2] - bf2f(h2)),
                               l3 = f2bf_rne(vv[3] - bf2f(h3));
                uint2 hw, lw;
                hw.x = (unsigned)h0 | ((unsigned)h1 << 16);
                hw.y = (unsigned)h2 | ((unsigned)h3 << 16);
                lw.x = (unsigned)l0 | ((unsigned)l1 << 16);
                lw.y = (unsigned)l2 | ((unsigned)l3 << 16);
                int kt2 = rbase >> 5;
                int sl  = (rbase >> 3) & 3;
                int e0  = rbase & 7;
                size_t so = ((size_t)(kt2 * 1024 + col) * 4 +
                             (sl ^ ((col >> 1) & 3))) * 8 + e0;
                *reinterpret_cast<uint2*>(&Woh[so]) = hw;
                *reinterpret_cast<uint2*>(&Wol[so]) = lw;
            }
        }
    }
}

// ---------------------------------------------------------------------------
template<int MODE>
__global__ __launch_bounds__(512, 2)
void mfma_gemm512(const float* __restrict__ Af,
                  const short* __restrict__ Bth, const short* __restrict__ Btl,
                  const float* __restrict__ bias,
                  const float* __restrict__ Sin,
                  float* __restrict__ Cf, int m)
{
    __shared__ __align__(16) short lds[2 * 5120 + 2 * 8192];
    gemm512_body<MODE, 0>(lds, blockIdx.x, blockIdx.y,
                          Af, Bth, Btl, bias, Sin, Cf, nullptr, nullptr, m);
}

// ---------------------------------------------------------------------------
// Fused [scan level (1024 blocks) + power squaring (32 blocks, WSPLIT)],
// all 128x256 tiles at 512 threads. Squares occupy by<8 (dispatch first).
// ---------------------------------------------------------------------------
__global__ __launch_bounds__(512, 2)
void fused_ls(const float* __restrict__ Sfrom, float* __restrict__ Sto,
              const float* __restrict__ Pfrom, float* __restrict__ Pto,
              const short* __restrict__ Bqh, const short* __restrict__ Bql,
              short* __restrict__ Bqoh, short* __restrict__ Bqol,
              int m)
{
    __shared__ __align__(16) short lds[2 * 5120 + 2 * 8192];
    if (blockIdx.y < 8) {
        gemm512_body<0, 1>(lds, blockIdx.x, blockIdx.y, Pfrom, Bqh, Bql,
                           nullptr, nullptr, Pto, Bqoh, Bqol, 0);
    } else {
        gemm512_body<1, 0>(lds, blockIdx.x, blockIdx.y - 8,
                           Sfrom, Bqh, Bql, nullptr, Sfrom, Sto,
                           nullptr, nullptr, m);
    }
}

// ---------------------------------------------------------------------------
// 256-thread split-precision body — kept ONLY for the MODE-2 carries
// (128 blocks, proven R6 structure).
// ---------------------------------------------------------------------------
__global__ __launch_bounds__(256, 2)
void carry_gemm(const float* __restrict__ Af,
                const short* __restrict__ Bth, const short* __restrict__ Btl,
                float* __restrict__ Cf, int tstart)
{
    constexpr int APL   = 5120;
    constexpr int BBASE = 2 * APL;
    constexpr int BPL   = 4096;          // 128*32
    __shared__ __align__(16) short lds[BBASE + 2 * BPL];

    const int tid  = threadIdx.x;
    const int lane = tid & 63;
    const int w    = tid >> 6;
    const int n0   = blockIdx.x * 128;
    const int m0g  = blockIdx.y * Tt + tstart;
    const int wm0  = (w >> 1) * 64;
    const int wn0  = (w & 1) * 64;
    const int ln   = lane & 15;
    const int ar   = tid >> 3;
    const int ac   = (tid & 7) * 4;

    int arow_src[4];
#pragma unroll
    for (int p = 0; p < 4; ++p)
        arow_src[p] = m0g + p * 32 + ar - 128;

    f32x4 acc[4][4];
#pragma unroll
    for (int i = 0; i < 4; ++i)
#pragma unroll
        for (int j = 0; j < 4; ++j) acc[i][j] = (f32x4){0.f, 0.f, 0.f, 0.f};

    int a_off[4];
#pragma unroll
    for (int i = 0; i < 4; ++i)
        a_off[i] = (wm0 + i * 16 + ln) * 40 + (lane >> 4) * 8;
    const int nlb    = wn0 + ln;
    const int b_off0 = BBASE + nlb * 32 +
                       (((lane >> 4) ^ ((nlb >> 1) & 3)) << 3);

    for (int kt = 0; kt < 32; ++kt) {
        __syncthreads();
#pragma unroll
        for (int p = 0; p < 4; ++p) {
            float4 v = *reinterpret_cast<const float4*>(
                &Af[(size_t)arow_src[p] * Dd + kt * 32 + ac]);
            int wo = (p * 32 + ar) * 40 + ac;
            unsigned short h0 = f2bf_rne(v.x), h1 = f2bf_rne(v.y),
                           h2 = f2bf_rne(v.z), h3 = f2bf_rne(v.w);
            unsigned short g0 = f2bf_rne(v.x - bf2f(h0)),
                           g1 = f2bf_rne(v.y - bf2f(h1)),
                           g2 = f2bf_rne(v.z - bf2f(h2)),
                           g3 = f2bf_rne(v.w - bf2f(h3));
            uint2 hw, lw;
            hw.x = (unsigned)h0 | ((unsigned)h1 << 16);
            hw.y = (unsigned)h2 | ((unsigned)h3 << 16);
            lw.x = (unsigned)g0 | ((unsigned)g1 << 16);
            lw.y = (unsigned)g2 | ((unsigned)g3 << 16);
            *reinterpret_cast<uint2*>(&lds[wo])       = hw;
            *reinterpret_cast<uint2*>(&lds[wo + APL]) = lw;
        }
#pragma unroll
        for (int q = 0; q < 2; ++q) {
            size_t gfo = ((size_t)(kt * 1024 + n0 + q * 64 + (tid >> 2))
                          * 4 + (tid & 3)) * 8;
            dma16(&Bth[gfo], &lds[BBASE + q * 2048 + w * 512]);
            dma16(&Btl[gfo], &lds[BBASE + BPL + q * 2048 + w * 512]);
        }
        __syncthreads();
        bf16x8 ah[4], al[4];
#pragma unroll
        for (int i = 0; i < 4; ++i) {
            ah[i] = *reinterpret_cast<const bf16x8*>(&lds[a_off[i]]);
            al[i] = *reinterpret_cast<const bf16x8*>(&lds[a_off[i] + APL]);
        }
#pragma unroll
        for (int j = 0; j < 4; ++j) {
            const bf16x8 bh = *reinterpret_cast<const bf16x8*>(
                &lds[b_off0 + j * 512]);
            const bf16x8 bl = *reinterpret_cast<const bf16x8*>(
                &lds[b_off0 + j * 512 + BPL]);
#pragma unroll
            for (int i = 0; i < 4; ++i) {
                acc[i][j] = __builtin_amdgcn_mfma_f32_16x16x32_bf16(
                    ah[i], bh, acc[i][j], 0, 0, 0);
                acc[i][j] = __builtin_amdgcn_mfma_f32_16x16x32_bf16(
                    ah[i], bl, acc[i][j], 0, 0, 0);
                acc[i][j] = __builtin_amdgcn_mfma_f32_16x16x32_bf16(
                    al[i], bh, acc[i][j], 0, 0, 0);
            }
        }
    }

#pragma unroll
    for (int j = 0; j < 4; ++j) {
        int col = n0 + wn0 + j * 16 + ln;
#pragma unroll
        for (int i = 0; i < 4; ++i) {
            int rbase = m0g + wm0 + i * 16 + (lane >> 4) * 4;
#pragma unroll
            for (int e = 0; e < 4; ++e) {
                size_t off = (size_t)(rbase + e) * Dd + col;
                Cf[off] += acc[i][j][e];
            }
        }
    }
}

// ---------------------------------------------------------------------------
// MLP GEMM (unchanged from R15): 512 thr, 128x256, bf16 hi-only, fused BN.
// ---------------------------------------------------------------------------
__global__ __launch_bounds__(512, 2)
void mlp_gemm(const float* __restrict__ Af,
              const short* __restrict__ Bth,
              const float* __restrict__ bias,
              float* __restrict__ Cf,
              float* __restrict__ psum, float* __restrict__ psq)
{
    constexpr int APL = 5120;
    constexpr int BB  = APL;
    __shared__ __align__(16) short lds[APL + 8192];

    const int tid  = threadIdx.x;
    const int lane = tid & 63;
    const int w    = tid >> 6;
    const int n0   = blockIdx.x * 256;
    const int m0g  = blockIdx.y * 128;
    const int wm0  = (w >> 2) * 64;
    const int wn0  = (w & 3) * 64;
    const int ln   = lane & 15;
    const int ar   = tid >> 2;
    const int ac   = (tid & 3) * 8;

    f32x4 acc[4][4];
#pragma unroll
    for (int i = 0; i < 4; ++i)
#pragma unroll
        for (int j = 0; j < 4; ++j) acc[i][j] = (f32x4){0.f, 0.f, 0.f, 0.f};

    int a_off[4];
#pragma unroll
    for (int i = 0; i < 4; ++i)
        a_off[i] = (wm0 + i * 16 + ln) * 40 + (lane >> 4) * 8;
    const int nlb    = wn0 + ln;
    const int b_off0 = BB + nlb * 32 +
                       (((lane >> 4) ^ ((nlb >> 1) & 3)) << 3);

    for (int kt = 0; kt < 32; ++kt) {
        __syncthreads();
        {
            const float* p = &Af[(size_t)(m0g + ar) * Dd + kt * 32 + ac];
            float4 v0 = *reinterpret_cast<const float4*>(p);
            float4 v1 = *reinterpret_cast<const float4*>(p + 4);
            unsigned short h0 = f2bf_rne(v0.x), h1 = f2bf_rne(v0.y),
                           h2 = f2bf_rne(v0.z), h3 = f2bf_rne(v0.w),
                           h4 = f2bf_rne(v1.x), h5 = f2bf_rne(v1.y),
                           h6 = f2bf_rne(v1.z), h7 = f2bf_rne(v1.w);
            int4 hw;
            hw.x = (int)((unsigned)h0 | ((unsigned)h1 << 16));
            hw.y = (int)((unsigned)h2 | ((unsigned)h3 << 16));
            hw.z = (int)((unsigned)h4 | ((unsigned)h5 << 16));
            hw.w = (int)((unsigned)h6 | ((unsigned)h7 << 16));
            *reinterpret_cast<int4*>(&lds[ar * 40 + ac]) = hw;
        }
#pragma unroll
        for (int q = 0; q < 2; ++q) {
            size_t gfo = ((size_t)(kt * 1024 + n0 + q * 128 + (tid >> 2))
                          * 4 + (tid & 3)) * 8;
            dma16(&Bth[gfo], &lds[BB + q * 4096 + w * 512]);
        }
        __syncthreads();
        bf16x8 ah[4];
#pragma unroll
        for (int i = 0; i < 4; ++i)
            ah[i] = *reinterpret_cast<const bf16x8*>(&lds[a_off[i]]);
#pragma unroll
        for (int j = 0; j < 4; ++j) {
            const bf16x8 bh = *reinterpret_cast<const bf16x8*>(
                &lds[b_off0 + j * 512]);
#pragma unroll
            for (int i = 0; i < 4; ++i)
                acc[i][j] = __builtin_amdgcn_mfma_f32_16x16x32_bf16(
                    ah[i], bh, acc[i][j], 0, 0, 0);
        }
    }

    float* bnF = reinterpret_cast<float*>(lds);
    __syncthreads();
    if (tid < 256) { bnF[tid] = 0.f; bnF[256 + tid] = 0.f; }
    __syncthreads();
#pragma unroll
    for (int j = 0; j < 4; ++j) {
        int cl  = wn0 + j * 16 + ln;
        int col = n0 + cl;
        float bj = bias[col];
        float sv = 0.f, sq = 0.f;
#pragma unroll
        for (int i = 0; i < 4; ++i) {
            int rbase = m0g + wm0 + i * 16 + (lane >> 4) * 4;
#pragma unroll
            for (int e = 0; e < 4; ++e) {
                size_t off = (size_t)(rbase + e) * Dd + col;
                float v = acc[i][j][e] + bj;
                Cf[off] = v;
                sv += v; sq += v * v;
            }
        }
        atomicAdd(&bnF[cl], sv); atomicAdd(&bnF[256 + cl], sq);
    }
    __syncthreads();
    if (tid < 256) {
        psum[(size_t)blockIdx.y * Dd + n0 + tid] = bnF[tid];
        psq [(size_t)blockIdx.y * Dd + n0 + tid] = bnF[256 + tid];
    }
}

// ---------------------------------------------------------------------------
__global__ __launch_bounds__(256)
void bn_stats(const float* __restrict__ ps, const float* __restrict__ pq,
              const float* __restrict__ scale, const float* __restrict__ bias,
              float* __restrict__ Av, float* __restrict__ Cv)
{
    const int d = blockIdx.x * 256 + threadIdx.x;
    float s = 0.f, q = 0.f;
    for (int p = 0; p < 256; ++p) {
        s += ps[p * Dd + d];
        q += pq[p * Dd + d];
    }
    const float invN = 1.0f / 32768.0f;
    float mean = s * invN;
    float var  = q * invN - mean * mean;
    float rs   = rsqrtf(var + 1e-5f);
    float a    = rs * scale[d];
    Av[d] = a;
    Cv[d] = bias[d] - mean * a;
}

// ---------------------------------------------------------------------------
__global__ __launch_bounds__(256)
void residual_gelu(const float* __restrict__ Z, const float* __restrict__ Yin,
                   float* __restrict__ Yout,
                   const float* __restrict__ Av, const float* __restrict__ Cv)
{
    const float4* z4 = reinterpret_cast<const float4*>(Z);
    const float4* y4 = reinterpret_cast<const float4*>(Yin);
    float4*       o4 = reinterpret_cast<float4*>(Yout);
    const float4* a4 = reinterpret_cast<const float4*>(Av);
    const float4* c4 = reinterpret_cast<const float4*>(Cv);
    const int n4 = MTOT * Dd / 4;
    for (int i = blockIdx.x * blockDim.x + threadIdx.x; i < n4;
         i += gridDim.x * blockDim.x) {
        int d4 = i & (Dd / 4 - 1);
        float4 z = z4[i], y = y4[i], a = a4[d4], c = c4[d4];
        float4 o;
        o.x = gelu_tanh(fmaf(z.x, a.x, c.x)) + y.x;
        o.y = gelu_tanh(fmaf(z.y, a.y, c.y)) + y.y;
        o.z = gelu_tanh(fmaf(z.z, a.z, c.z)) + y.z;
        o.w = gelu_tanh(fmaf(z.w, a.w, c.w)) + y.w;
        o4[i] = o;
    }
}

// ---------------------------------------------------------------------------
extern "C" void kernel_launch(void* const* d_in, const int* in_sizes, int n_in,
                              void* d_out, int out_size, void* d_ws, size_t ws_size,
                              hipStream_t stream)
{
    const float* x    = (const float*)d_in[0];
    const float* Wi   = (const float*)d_in[1];
    const float* bi   = (const float*)d_in[2];
    const float* Wh   = (const float*)d_in[3];
    const float* mlpW = (const float*)d_in[4];
    const float* mlpb = (const float*)d_in[5];
    const float* bns  = (const float*)d_in[6];
    const float* bnb  = (const float*)d_in[7];
    float* out = (float*)d_out;

    const size_t NE = (size_t)MTOT * Dd;
    const size_t MM = (size_t)Dd * Dd;       // 1M
    float* ws   = (float*)d_ws;
    float* S0   = ws;                        // 32M floats (128 MiB)
    float* Pa   = S0 + NE;
    float* Pb   = Pa + MM;
    float* psum = Pb + MM;                   // [256][1024]
    float* psq  = psum + 256 * Dd;
    float* abuf = psq + 256 * Dd;
    float* cbuf = abuf + Dd;
    short* Bq0h = (short*)(cbuf + Dd);       // split buffers, 1M shorts each
    short* Bq0l = Bq0h + MM;
    short* Bq1h = Bq0l + MM;
    short* Bq1l = Bq1h + MM;
    short* BmH[NL]; short* BmL[NL];
    {
        short* p = Bq1l + MM;
        for (int l = 0; l < NL; ++l) { BmH[l] = p; p += MM; BmL[l] = p; p += MM; }
    }

    const dim3 gBig(4, 256);    // 128x256 tiles
    const dim3 gF  (4, 264);    // fused: 8 square-rows + 256 level-rows
    const dim3 gSeq(8, 16);     // carries: 128x128 tiles
    const dim3 gBt (32, 32);

    // ---- all input-matrix splits upfront ----
    split_bt<<<gBt, 256, 0, stream>>>(Wi, Bq0h, Bq0l);
    split_bt<<<gBt, 256, 0, stream>>>(Wh, Bq1h, Bq1l);
    for (int l = 0; l < NL; ++l)
        split_bt<<<gBt, 256, 0, stream>>>(mlpW + (size_t)l * MM, BmH[l], BmL[l]);

    // ---- Phase 1: xp = x @ Wi + bi -> S0 (512-thr, 16 waves/CU) ----
    mfma_gemm512<0><<<gBig, 512, 0, stream>>>(
        x, Bq0h, Bq0l, bi, nullptr, S0, 0);

    // ---- Phase 2: 7 fused [level + squaring] launches (512-thr) ----
    fused_ls<<<gF, 512, 0, stream>>>(S0, out, Wh, Pa, Bq1h, Bq1l, Bq0h, Bq0l, 1);
    fused_ls<<<gF, 512, 0, stream>>>(out, S0, Pa, Pb, Bq0h, Bq0l, Bq1h, Bq1l, 2);
    fused_ls<<<gF, 512, 0, stream>>>(S0, out, Pb, Pa, Bq1h, Bq1l, Bq0h, Bq0l, 4);
    fused_ls<<<gF, 512, 0, stream>>>(out, S0, Pa, Pb, Bq0h, Bq0l, Bq1h, Bq1l, 8);
    fused_ls<<<gF, 512, 0, stream>>>(S0, out, Pb, Pa, Bq1h, Bq1l, Bq0h, Bq0l, 16);
    fused_ls<<<gF, 512, 0, stream>>>(out, S0, Pa, Pb, Bq0h, Bq0l, Bq1h, Bq1l, 32);
    fused_ls<<<gF, 512, 0, stream>>>(S0, out, Pb, Pa, Bq1h, Bq1l, Bq0h, Bq0l, 64);
    // state now in `out`; split(P128) now in Bq0.

    // ---- Phase 3: 15 sequential carry steps with P128 (in-place on out) ----
    for (int i = 1; i < 16; ++i)
        carry_gemm<<<gSeq, 256, 0, stream>>>(out, Bq0h, Bq0l, out, 128 * i);

    // ---- Phase 4: residual MLP stack (512-thr bf16 GEMMs); y in out, z->S0 ----
    for (int l = 0; l < NL; ++l) {
        mlp_gemm<<<gBig, 512, 0, stream>>>(
            out, BmH[l], mlpb + (size_t)l * Dd, S0, psum, psq);
        bn_stats<<<4, 256, 0, stream>>>(psum, psq, bns + (size_t)l * Dd,
                                        bnb + (size_t)l * Dd, abuf, cbuf);
        residual_gelu<<<2048, 256, 0, stream>>>(S0, out, out, abuf, cbuf);
    }
}

// Round 17
// 3590.491 us; speedup vs baseline: 1.2530x; 1.2530x over previous
//
#include <hip/hip_runtime.h>
#include <math.h>

#define Bb   16
#define Tt   2048
#define Dd   1024
#define NL   4
#define MTOT (Bb * Tt)   // 32768

typedef float f32x4 __attribute__((ext_vector_type(4)));
typedef short bf16x8 __attribute__((ext_vector_type(8)));

// ---------------------------------------------------------------------------
__device__ __forceinline__ unsigned short f2bf_rne(float x) {
    unsigned u = __float_as_uint(x);
    u += 0x7fffu + ((u >> 16) & 1u);
    return (unsigned short)(u >> 16);
}
__device__ __forceinline__ float bf2f(unsigned short h) {
    return __uint_as_float(((unsigned)h) << 16);
}
__device__ __forceinline__ float gelu_tanh(float x) {
    float x3 = x * x * x;
    float u  = 0.7978845608028654f * (x + 0.044715f * x3);
    return 0.5f * x * (1.0f + tanhf(u));
}
// async 16B global -> LDS (HW: wave-uniform LDS base + lane*16)
__device__ __forceinline__ void dma16(const void* g, void* l) {
    __builtin_amdgcn_global_load_lds(
        (const __attribute__((address_space(1))) unsigned int*)g,
        (__attribute__((address_space(3))) unsigned int*)l, 16, 0, 0);
}

// ---------------------------------------------------------------------------
// Split a [1024,1024] fp32 matrix (row-major [k][n]) into bf16 hi/lo with
// k-tiled, slot-swizzled layout (proven R6 B-path):
//   element (k,n): kt=k>>5, sl=(k>>3)&3, e=k&7
//   shorts offset = ((kt*1024+n)*4 + (sl^((n>>1)&3)))*8 + e
// ---------------------------------------------------------------------------
__global__ __launch_bounds__(256)
void split_bt(const float* __restrict__ B, short* __restrict__ ht,
              short* __restrict__ lt)
{
    __shared__ float tile[32][33];
    const int t  = threadIdx.x;
    const int r  = t >> 3;          // 0..31
    const int c  = (t & 7) * 4;     // 0,4,...,28
    const int kb = blockIdx.y * 32; // kt = blockIdx.y
    const int nb = blockIdx.x * 32;
    float4 v = *reinterpret_cast<const float4*>(
        &B[(size_t)(kb + r) * Dd + nb + c]);
    tile[r][c + 0] = v.x; tile[r][c + 1] = v.y;
    tile[r][c + 2] = v.z; tile[r][c + 3] = v.w;
    __syncthreads();
    unsigned h[4], lo[4];
#pragma unroll
    for (int q = 0; q < 4; ++q) {
        float f = tile[c + q][r];           // B[kb+c+q][nb+r]
        unsigned short hh = f2bf_rne(f);
        float rem = f - bf2f(hh);
        h[q]  = hh;
        lo[q] = f2bf_rne(rem);
    }
    uint2 hw, lw;
    hw.x = h[0]  | (h[1]  << 16); hw.y = h[2]  | (h[3]  << 16);
    lw.x = lo[0] | (lo[1] << 16); lw.y = lo[2] | (lo[3] << 16);
    const int n = nb + r;
    const int s = (c >> 3) ^ ((n >> 1) & 3);   // swizzled slot
    size_t off = ((size_t)(blockIdx.y * 1024 + n) * 4 + s) * 8 + (c & 4);
    *reinterpret_cast<uint2*>(&ht[off]) = hw;
    *reinterpret_cast<uint2*>(&lt[off]) = lw;
}

// ---------------------------------------------------------------------------
// R6-proven split-precision MFMA GEMM body (device function, inlined).
// Tile 128xNT, BK=32, 256 thr = 4 waves (2x2), two barriers per k-tile,
// A fp32 reg->convert->ds_write, B via dma16 from pre-split layout.
// S3=1: split precision (hi+lo planes, 3 MFMA). S3=0: bf16 hi-only (1 MFMA).
// MODE 0: C = A@B (+bias); MODE 1: C[t]=Sin[t]+(t%Tt>=m ? A[t-m]@B : 0);
// MODE 2: rows [tstart,tstart+128) per batch: C[r]=Sin[r]+A[r-128]@B.
// WSPLIT=1: epilogue also writes C into the split/swizzled B-layout.
// ---------------------------------------------------------------------------
template<int MODE, int NT, int S3, int WSPLIT>
__device__ __forceinline__ void gemm_body(
    short* lds, int bx, int by,
    const float* __restrict__ Af,
    const short* __restrict__ Bth, const short* __restrict__ Btl,
    const float* __restrict__ bias,
    const float* __restrict__ Sin,
    float* __restrict__ Cf,
    short* __restrict__ Woh, short* __restrict__ Wol,
    int m, int tstart)
{
    constexpr int NJ    = NT / 32;
    constexpr int APL   = 5120;              // shorts per A plane (128*40)
    constexpr int BBASE = (S3 ? 2 : 1) * APL;
    constexpr int BPL   = NT * 32;           // shorts per B plane

    const int tid  = threadIdx.x;
    const int lane = tid & 63;
    const int w    = tid >> 6;
    const int n0   = bx * NT;
    const int m0g  = (MODE == 2) ? (by * Tt + tstart) : (by * 128);
    const int wm0  = (w >> 1) * 64;
    const int wn0  = (w & 1) * (NT / 2);
    const int ln   = lane & 15;
    const int ar   = tid >> 3;
    const int ac   = (tid & 7) * 4;

    int  arow_src[4]; bool avalid[4];
#pragma unroll
    for (int p = 0; p < 4; ++p) {
        int rg = m0g + p * 32 + ar;
        bool v = true;
        if (MODE == 1) v = ((rg & (Tt - 1)) >= m);
        avalid[p]   = v;
        arow_src[p] = (MODE >= 1 && v) ? (rg - m) : rg;
    }

    f32x4 acc[4][NJ];
#pragma unroll
    for (int i = 0; i < 4; ++i)
#pragma unroll
        for (int j = 0; j < NJ; ++j) acc[i][j] = (f32x4){0.f, 0.f, 0.f, 0.f};

    int a_off[4];
#pragma unroll
    for (int i = 0; i < 4; ++i)
        a_off[i] = (wm0 + i * 16 + ln) * 40 + (lane >> 4) * 8;
    const int nlb    = wn0 + ln;
    const int b_off0 = BBASE + nlb * 32 +
                       (((lane >> 4) ^ ((nlb >> 1) & 3)) << 3);

    for (int kt = 0; kt < 32; ++kt) {
        __syncthreads();   // previous tile's ds_reads complete
        // ---- stage A: global fp32 -> bf16 (hi [+lo]) -> LDS ----
#pragma unroll
        for (int p = 0; p < 4; ++p) {
            float4 v = *reinterpret_cast<const float4*>(
                &Af[(size_t)arow_src[p] * Dd + kt * 32 + ac]);
            if (MODE == 1 && !avalid[p]) v = make_float4(0.f, 0.f, 0.f, 0.f);
            int wo = (p * 32 + ar) * 40 + ac;
            unsigned short h0 = f2bf_rne(v.x), h1 = f2bf_rne(v.y),
                           h2 = f2bf_rne(v.z), h3 = f2bf_rne(v.w);
            uint2 hw;
            hw.x = (unsigned)h0 | ((unsigned)h1 << 16);
            hw.y = (unsigned)h2 | ((unsigned)h3 << 16);
            *reinterpret_cast<uint2*>(&lds[wo]) = hw;
            if (S3) {
                unsigned short g0 = f2bf_rne(v.x - bf2f(h0)),
                               g1 = f2bf_rne(v.y - bf2f(h1)),
                               g2 = f2bf_rne(v.z - bf2f(h2)),
                               g3 = f2bf_rne(v.w - bf2f(h3));
                uint2 lw;
                lw.x = (unsigned)g0 | ((unsigned)g1 << 16);
                lw.y = (unsigned)g2 | ((unsigned)g3 << 16);
                *reinterpret_cast<uint2*>(&lds[wo + APL]) = lw;
            }
        }
        // ---- stage B: async DMA from pre-split swizzled layout ----
#pragma unroll
        for (int q = 0; q < (NT > 64 ? NT / 64 : 1); ++q) {
            int nidx = (NT >= 64) ? (q * 64 + (tid >> 2)) : 0;
            size_t gfo = ((size_t)(kt * 1024 + n0 + nidx) * 4 + (tid & 3)) * 8;
            dma16(&Bth[gfo], &lds[BBASE + q * 2048 + w * 512]);
            if (S3)
                dma16(&Btl[gfo], &lds[BBASE + BPL + q * 2048 + w * 512]);
        }
        __syncthreads();   // drains vmcnt (DMA) + lgkm (A writes)
        // ---- compute ----
        bf16x8 ah[4], al[4];
#pragma unroll
        for (int i = 0; i < 4; ++i) {
            ah[i] = *reinterpret_cast<const bf16x8*>(&lds[a_off[i]]);
            if (S3)
                al[i] = *reinterpret_cast<const bf16x8*>(&lds[a_off[i] + APL]);
        }
#pragma unroll
        for (int j = 0; j < NJ; ++j) {
            const bf16x8 bh = *reinterpret_cast<const bf16x8*>(
                &lds[b_off0 + j * 512]);
#pragma unroll
            for (int i = 0; i < 4; ++i)
                acc[i][j] = __builtin_amdgcn_mfma_f32_16x16x32_bf16(
                    ah[i], bh, acc[i][j], 0, 0, 0);
            if (S3) {
                const bf16x8 bl = *reinterpret_cast<const bf16x8*>(
                    &lds[b_off0 + j * 512 + BPL]);
#pragma unroll
                for (int i = 0; i < 4; ++i) {
                    acc[i][j] = __builtin_amdgcn_mfma_f32_16x16x32_bf16(
                        ah[i], bl, acc[i][j], 0, 0, 0);
                    acc[i][j] = __builtin_amdgcn_mfma_f32_16x16x32_bf16(
                        al[i], bh, acc[i][j], 0, 0, 0);
                }
            }
        }
    }

    // ---- epilogue ----
#pragma unroll
    for (int j = 0; j < NJ; ++j) {
        int cl  = wn0 + j * 16 + ln;
        int col = n0 + cl;
        float bj = (MODE == 0 && bias) ? bias[col] : 0.f;
#pragma unroll
        for (int i = 0; i < 4; ++i) {
            int rbase = m0g + wm0 + i * 16 + (lane >> 4) * 4;
            float vv[4];
#pragma unroll
            for (int e = 0; e < 4; ++e) {
                size_t off = (size_t)(rbase + e) * Dd + col;
                float v = acc[i][j][e] + bj;
                if (MODE >= 1) v += Sin[off];
                Cf[off] = v;
                vv[e] = v;
            }
            if (WSPLIT) {
                unsigned short h0 = f2bf_rne(vv[0]), h1 = f2bf_rne(vv[1]),
                               h2 = f2bf_rne(vv[2]), h3 = f2bf_rne(vv[3]);
                unsigned short l0 = f2bf_rne(vv[0] - bf2f(h0)),
                               l1 = f2bf_rne(vv[1] - bf2f(h1)),
                               l2 = f2bf_rne(vv[2] - bf2f(h2)),
                               l3 = f2bf_rne(vv[3] - bf2f(h3));
                uint2 hw, lw;
                hw.x = (unsigned)h0 | ((unsigned)h1 << 16);
                hw.y = (unsigned)h2 | ((unsigned)h3 << 16);
                lw.x = (unsigned)l0 | ((unsigned)l1 << 16);
                lw.y = (unsigned)l2 | ((unsigned)l3 << 16);
                int kt2 = rbase >> 5;
                int sl  = (rbase >> 3) & 3;
                int e0  = rbase & 7;
                size_t so = ((size_t)(kt2 * 1024 + col) * 4 +
                             (sl ^ ((col >> 1) & 3))) * 8 + e0;
                *reinterpret_cast<uint2*>(&Woh[so]) = hw;
                *reinterpret_cast<uint2*>(&Wol[so]) = lw;
            }
        }
    }
}

// ---------------------------------------------------------------------------
template<int MODE, int NT, int S3>
__global__ __launch_bounds__(256, 2)
void mfma_gemm(const float* __restrict__ Af,
               const short* __restrict__ Bth, const short* __restrict__ Btl,
               const float* __restrict__ bias,
               const float* __restrict__ Sin,
               float* __restrict__ Cf,
               int m, int tstart)
{
    constexpr int LSZ = (S3 ? 2 : 1) * (5120 + NT * 32);
    __shared__ __align__(16) short lds[LSZ];
    gemm_body<MODE, NT, S3, 0>(lds, blockIdx.x, blockIdx.y,
                               Af, Bth, Btl, bias, Sin, Cf,
                               nullptr, nullptr, m, tstart);
}

// ---------------------------------------------------------------------------
// Fused [scan level (1024 blocks, NT=256) + power squaring (64 blocks,
// NT=128, WSPLIT)] launch. Squares occupy by<16 (dispatch first).
// ---------------------------------------------------------------------------
__global__ __launch_bounds__(256, 2)
void fused_ls(const float* __restrict__ Sfrom, float* __restrict__ Sto,
              const float* __restrict__ Pfrom, float* __restrict__ Pto,
              const short* __restrict__ Bqh, const short* __restrict__ Bql,
              short* __restrict__ Bqoh, short* __restrict__ Bqol,
              int m)
{
    __shared__ __align__(16) short lds[2 * (5120 + 8192)];
    if (blockIdx.y < 16) {
        int sq  = blockIdx.y;
        int sbx = blockIdx.x + ((sq & 1) << 2);
        int sby = sq >> 1;
        gemm_body<0, 128, 1, 1>(lds, sbx, sby, Pfrom, Bqh, Bql,
                                nullptr, nullptr, Pto, Bqoh, Bqol, 0, 0);
    } else {
        gemm_body<1, 256, 1, 0>(lds, blockIdx.x, blockIdx.y - 16,
                                Sfrom, Bqh, Bql, nullptr, Sfrom, Sto,
                                nullptr, nullptr, m, 0);
    }
}

// ---------------------------------------------------------------------------
// MLP GEMM (R15-proven): 512 thr, 128x256, bf16 hi-only, fused BN partials.
// ---------------------------------------------------------------------------
__global__ __launch_bounds__(512, 2)
void mlp_gemm(const float* __restrict__ Af,
              const short* __restrict__ Bth,
              const float* __restrict__ bias,
              float* __restrict__ Cf,
              float* __restrict__ psum, float* __restrict__ psq)
{
    constexpr int APL = 5120;
    constexpr int BB  = APL;
    __shared__ __align__(16) short lds[APL + 8192];

    const int tid  = threadIdx.x;
    const int lane = tid & 63;
    const int w    = tid >> 6;
    const int n0   = blockIdx.x * 256;
    const int m0g  = blockIdx.y * 128;
    const int wm0  = (w >> 2) * 64;
    const int wn0  = (w & 3) * 64;
    const int ln   = lane & 15;
    const int ar   = tid >> 2;
    const int ac   = (tid & 3) * 8;

    f32x4 acc[4][4];
#pragma unroll
    for (int i = 0; i < 4; ++i)
#pragma unroll
        for (int j = 0; j < 4; ++j) acc[i][j] = (f32x4){0.f, 0.f, 0.f, 0.f};

    int a_off[4];
#pragma unroll
    for (int i = 0; i < 4; ++i)
        a_off[i] = (wm0 + i * 16 + ln) * 40 + (lane >> 4) * 8;
    const int nlb    = wn0 + ln;
    const int b_off0 = BB + nlb * 32 +
                       (((lane >> 4) ^ ((nlb >> 1) & 3)) << 3);

    for (int kt = 0; kt < 32; ++kt) {
        __syncthreads();
        {
            const float* p = &Af[(size_t)(m0g + ar) * Dd + kt * 32 + ac];
            float4 v0 = *reinterpret_cast<const float4*>(p);
            float4 v1 = *reinterpret_cast<const float4*>(p + 4);
            unsigned short h0 = f2bf_rne(v0.x), h1 = f2bf_rne(v0.y),
                           h2 = f2bf_rne(v0.z), h3 = f2bf_rne(v0.w),
                           h4 = f2bf_rne(v1.x), h5 = f2bf_rne(v1.y),
                           h6 = f2bf_rne(v1.z), h7 = f2bf_rne(v1.w);
            int4 hw;
            hw.x = (int)((unsigned)h0 | ((unsigned)h1 << 16));
            hw.y = (int)((unsigned)h2 | ((unsigned)h3 << 16));
            hw.z = (int)((unsigned)h4 | ((unsigned)h5 << 16));
            hw.w = (int)((unsigned)h6 | ((unsigned)h7 << 16));
            *reinterpret_cast<int4*>(&lds[ar * 40 + ac]) = hw;
        }
#pragma unroll
        for (int q = 0; q < 2; ++q) {
            size_t gfo = ((size_t)(kt * 1024 + n0 + q * 128 + (tid >> 2))
                          * 4 + (tid & 3)) * 8;
            dma16(&Bth[gfo], &lds[BB + q * 4096 + w * 512]);
        }
        __syncthreads();
        bf16x8 ah[4];
#pragma unroll
        for (int i = 0; i < 4; ++i)
            ah[i] = *reinterpret_cast<const bf16x8*>(&lds[a_off[i]]);
#pragma unroll
        for (int j = 0; j < 4; ++j) {
            const bf16x8 bh = *reinterpret_cast<const bf16x8*>(
                &lds[b_off0 + j * 512]);
#pragma unroll
            for (int i = 0; i < 4; ++i)
                acc[i][j] = __builtin_amdgcn_mfma_f32_16x16x32_bf16(
                    ah[i], bh, acc[i][j], 0, 0, 0);
        }
    }

    float* bnF = reinterpret_cast<float*>(lds);
    __syncthreads();
    if (tid < 256) { bnF[tid] = 0.f; bnF[256 + tid] = 0.f; }
    __syncthreads();
#pragma unroll
    for (int j = 0; j < 4; ++j) {
        int cl  = wn0 + j * 16 + ln;
        int col = n0 + cl;
        float bj = bias[col];
        float sv = 0.f, sq = 0.f;
#pragma unroll
        for (int i = 0; i < 4; ++i) {
            int rbase = m0g + wm0 + i * 16 + (lane >> 4) * 4;
#pragma unroll
            for (int e = 0; e < 4; ++e) {
                size_t off = (size_t)(rbase + e) * Dd + col;
                float v = acc[i][j][e] + bj;
                Cf[off] = v;
                sv += v; sq += v * v;
            }
        }
        atomicAdd(&bnF[cl], sv); atomicAdd(&bnF[256 + cl], sq);
    }
    __syncthreads();
    if (tid < 256) {
        psum[(size_t)blockIdx.y * Dd + n0 + tid] = bnF[tid];
        psq [(size_t)blockIdx.y * Dd + n0 + tid] = bnF[256 + tid];
    }
}

// ---------------------------------------------------------------------------
__global__ __launch_bounds__(256)
void bn_stats(const float* __restrict__ ps, const float* __restrict__ pq,
              const float* __restrict__ scale, const float* __restrict__ bias,
              float* __restrict__ Av, float* __restrict__ Cv)
{
    const int d = blockIdx.x * 256 + threadIdx.x;
    float s = 0.f, q = 0.f;
    for (int p = 0; p < 256; ++p) {
        s += ps[p * Dd + d];
        q += pq[p * Dd + d];
    }
    const float invN = 1.0f / 32768.0f;
    float mean = s * invN;
    float var  = q * invN - mean * mean;
    float rs   = rsqrtf(var + 1e-5f);
    float a    = rs * scale[d];
    Av[d] = a;
    Cv[d] = bias[d] - mean * a;
}

// ---------------------------------------------------------------------------
__global__ __launch_bounds__(256)
void residual_gelu(const float* __restrict__ Z, const float* __restrict__ Yin,
                   float* __restrict__ Yout,
                   const float* __restrict__ Av, const float* __restrict__ Cv)
{
    const float4* z4 = reinterpret_cast<const float4*>(Z);
    const float4* y4 = reinterpret_cast<const float4*>(Yin);
    float4*       o4 = reinterpret_cast<float4*>(Yout);
    const float4* a4 = reinterpret_cast<const float4*>(Av);
    const float4* c4 = reinterpret_cast<const float4*>(Cv);
    const int n4 = MTOT * Dd / 4;
    for (int i = blockIdx.x * blockDim.x + threadIdx.x; i < n4;
         i += gridDim.x * blockDim.x) {
        int d4 = i & (Dd / 4 - 1);
        float4 z = z4[i], y = y4[i], a = a4[d4], c = c4[d4];
        float4 o;
        o.x = gelu_tanh(fmaf(z.x, a.x, c.x)) + y.x;
        o.y = gelu_tanh(fmaf(z.y, a.y, c.y)) + y.y;
        o.z = gelu_tanh(fmaf(z.z, a.z, c.z)) + y.z;
        o.w = gelu_tanh(fmaf(z.w, a.w, c.w)) + y.w;
        o4[i] = o;
    }
}

// ---------------------------------------------------------------------------
extern "C" void kernel_launch(void* const* d_in, const int* in_sizes, int n_in,
                              void* d_out, int out_size, void* d_ws, size_t ws_size,
                              hipStream_t stream)
{
    const float* x    = (const float*)d_in[0];
    const float* Wi   = (const float*)d_in[1];
    const float* bi   = (const float*)d_in[2];
    const float* Wh   = (const float*)d_in[3];
    const float* mlpW = (const float*)d_in[4];
    const float* mlpb = (const float*)d_in[5];
    const float* bns  = (const float*)d_in[6];
    const float* bnb  = (const float*)d_in[7];
    float* out = (float*)d_out;

    const size_t NE = (size_t)MTOT * Dd;
    const size_t MM = (size_t)Dd * Dd;       // 1M
    float* ws   = (float*)d_ws;
    float* S0   = ws;                        // 32M floats (128 MiB)
    float* Pa   = S0 + NE;
    float* Pb   = Pa + MM;
    float* psum = Pb + MM;                   // [256][1024]
    float* psq  = psum + 256 * Dd;
    float* abuf = psq + 256 * Dd;
    float* cbuf = abuf + Dd;
    short* Bq0h = (short*)(cbuf + Dd);       // split buffers, 1M shorts each
    short* Bq0l = Bq0h + MM;
    short* Bq1h = Bq0l + MM;
    short* Bq1l = Bq1h + MM;
    short* BmH[NL]; short* BmL[NL];
    {
        short* p = Bq1l + MM;
        for (int l = 0; l < NL; ++l) { BmH[l] = p; p += MM; BmL[l] = p; p += MM; }
    }

    const dim3 gBig(4, 256);    // 128x256 tiles, 256 thr
    const dim3 gF  (4, 272);    // fused: 16 square-rows + 256 level-rows
    const dim3 gSeq(16, 16);    // carries: 128x64 tiles (256 blocks, all CUs)
    const dim3 gBt (32, 32);

    // ---- all input-matrix splits upfront ----
    split_bt<<<gBt, 256, 0, stream>>>(Wi, Bq0h, Bq0l);
    split_bt<<<gBt, 256, 0, stream>>>(Wh, Bq1h, Bq1l);
    for (int l = 0; l < NL; ++l)
        split_bt<<<gBt, 256, 0, stream>>>(mlpW + (size_t)l * MM, BmH[l], BmL[l]);

    // ---- Phase 1: xp = x @ Wi + bi -> S0 ----
    mfma_gemm<0, 256, 1><<<gBig, 256, 0, stream>>>(
        x, Bq0h, Bq0l, bi, nullptr, S0, 0, 0);

    // ---- Phase 2: 7 fused [level + squaring] launches ----
    fused_ls<<<gF, 256, 0, stream>>>(S0, out, Wh, Pa, Bq1h, Bq1l, Bq0h, Bq0l, 1);
    fused_ls<<<gF, 256, 0, stream>>>(out, S0, Pa, Pb, Bq0h, Bq0l, Bq1h, Bq1l, 2);
    fused_ls<<<gF, 256, 0, stream>>>(S0, out, Pb, Pa, Bq1h, Bq1l, Bq0h, Bq0l, 4);
    fused_ls<<<gF, 256, 0, stream>>>(out, S0, Pa, Pb, Bq0h, Bq0l, Bq1h, Bq1l, 8);
    fused_ls<<<gF, 256, 0, stream>>>(S0, out, Pb, Pa, Bq1h, Bq1l, Bq0h, Bq0l, 16);
    fused_ls<<<gF, 256, 0, stream>>>(out, S0, Pa, Pb, Bq0h, Bq0l, Bq1h, Bq1l, 32);
    fused_ls<<<gF, 256, 0, stream>>>(S0, out, Pb, Pa, Bq1h, Bq1l, Bq0h, Bq0l, 64);
    // state now in `out`; split(P128) now in Bq0.

    // ---- Phase 3: 15 sequential carry steps with P128 (in-place on out),
    //      NT=64 tiles -> 256 blocks = every CU busy ----
    for (int i = 1; i < 16; ++i)
        mfma_gemm<2, 64, 1><<<gSeq, 256, 0, stream>>>(
            out, Bq0h, Bq0l, nullptr, out, out, 128, 128 * i);

    // ---- Phase 4: residual MLP stack (512-thr bf16 GEMMs); y in out, z->S0 ----
    for (int l = 0; l < NL; ++l) {
        mlp_gemm<<<gBig, 512, 0, stream>>>(
            out, BmH[l], mlpb + (size_t)l * Dd, S0, psum, psq);
        bn_stats<<<4, 256, 0, stream>>>(psum, psq, bns + (size_t)l * Dd,
                                        bnb + (size_t)l * Dd, abuf, cbuf);
        residual_gelu<<<2048, 256, 0, stream>>>(S0, out, out, abuf, cbuf);
    }
}

// Round 18
// 3528.714 us; speedup vs baseline: 1.2749x; 1.0175x over previous
//
#include <hip/hip_runtime.h>
#include <math.h>

#define Bb   16
#define Tt   2048
#define Dd   1024
#define NL   4
#define MTOT (Bb * Tt)   // 32768

typedef float f32x4 __attribute__((ext_vector_type(4)));
typedef short bf16x8 __attribute__((ext_vector_type(8)));

// ---------------------------------------------------------------------------
__device__ __forceinline__ unsigned short f2bf_rne(float x) {
    unsigned u = __float_as_uint(x);
    u += 0x7fffu + ((u >> 16) & 1u);
    return (unsigned short)(u >> 16);
}
__device__ __forceinline__ float bf2f(unsigned short h) {
    return __uint_as_float(((unsigned)h) << 16);
}
__device__ __forceinline__ float gelu_tanh(float x) {
    float x3 = x * x * x;
    float u  = 0.7978845608028654f * (x + 0.044715f * x3);
    return 0.5f * x * (1.0f + tanhf(u));
}
// async 16B global -> LDS (HW: wave-uniform LDS base + lane*16)
__device__ __forceinline__ void dma16(const void* g, void* l) {
    __builtin_amdgcn_global_load_lds(
        (const __attribute__((address_space(1))) unsigned int*)g,
        (__attribute__((address_space(3))) unsigned int*)l, 16, 0, 0);
}

// ---------------------------------------------------------------------------
// Split a [1024,1024] fp32 matrix (row-major [k][n]) into bf16 hi/lo with
// k-tiled, slot-swizzled layout (proven R6 B-path):
//   element (k,n): kt=k>>5, sl=(k>>3)&3, e=k&7
//   shorts offset = ((kt*1024+n)*4 + (sl^((n>>1)&3)))*8 + e
// ---------------------------------------------------------------------------
__global__ __launch_bounds__(256)
void split_bt(const float* __restrict__ B, short* __restrict__ ht,
              short* __restrict__ lt)
{
    __shared__ float tile[32][33];
    const int t  = threadIdx.x;
    const int r  = t >> 3;          // 0..31
    const int c  = (t & 7) * 4;     // 0,4,...,28
    const int kb = blockIdx.y * 32; // kt = blockIdx.y
    const int nb = blockIdx.x * 32;
    float4 v = *reinterpret_cast<const float4*>(
        &B[(size_t)(kb + r) * Dd + nb + c]);
    tile[r][c + 0] = v.x; tile[r][c + 1] = v.y;
    tile[r][c + 2] = v.z; tile[r][c + 3] = v.w;
    __syncthreads();
    unsigned h[4], lo[4];
#pragma unroll
    for (int q = 0; q < 4; ++q) {
        float f = tile[c + q][r];           // B[kb+c+q][nb+r]
        unsigned short hh = f2bf_rne(f);
        float rem = f - bf2f(hh);
        h[q]  = hh;
        lo[q] = f2bf_rne(rem);
    }
    uint2 hw, lw;
    hw.x = h[0]  | (h[1]  << 16); hw.y = h[2]  | (h[3]  << 16);
    lw.x = lo[0] | (lo[1] << 16); lw.y = lo[2] | (lo[3] << 16);
    const int n = nb + r;
    const int s = (c >> 3) ^ ((n >> 1) & 3);   // swizzled slot
    size_t off = ((size_t)(blockIdx.y * 1024 + n) * 4 + s) * 8 + (c & 4);
    *reinterpret_cast<uint2*>(&ht[off]) = hw;
    *reinterpret_cast<uint2*>(&lt[off]) = lw;
}

// ---------------------------------------------------------------------------
// R6-proven split-precision MFMA GEMM body (device function, inlined).
// Tile 128xNT, BK=32, 256 thr = 4 waves (2x2), two barriers per k-tile.
// A planes now use the SAME 32-short XOR-swizzled granule layout as B
// (saves 4 KB LDS vs the 40-pad -> 3 blocks/CU headroom); write slot
// (k>>3)^((row>>1)&3), read with identical XOR (involution).
// S3=1: split precision (hi+lo planes, 3 MFMA). S3=0: bf16 hi-only (1 MFMA).
// MODE 0: C = A@B (+bias); MODE 1: C[t]=Sin[t]+(t%Tt>=m ? A[t-m]@B : 0);
// MODE 2: rows [tstart,tstart+128) per batch: C[r]=Sin[r]+A[r-128]@B.
// WSPLIT=1: epilogue also writes C into the split/swizzled B-layout.
// ---------------------------------------------------------------------------
template<int MODE, int NT, int S3, int WSPLIT>
__device__ __forceinline__ void gemm_body(
    short* lds, int bx, int by,
    const float* __restrict__ Af,
    const short* __restrict__ Bth, const short* __restrict__ Btl,
    const float* __restrict__ bias,
    const float* __restrict__ Sin,
    float* __restrict__ Cf,
    short* __restrict__ Woh, short* __restrict__ Wol,
    int m, int tstart)
{
    constexpr int NJ    = NT / 32;
    constexpr int APL   = 4096;              // shorts per A plane (128*32)
    constexpr int BBASE = (S3 ? 2 : 1) * APL;
    constexpr int BPL   = NT * 32;           // shorts per B plane

    const int tid  = threadIdx.x;
    const int lane = tid & 63;
    const int w    = tid >> 6;
    const int n0   = bx * NT;
    const int m0g  = (MODE == 2) ? (by * Tt + tstart) : (by * 128);
    const int wm0  = (w >> 1) * 64;
    const int wn0  = (w & 1) * (NT / 2);
    const int ln   = lane & 15;
    const int ar   = tid >> 3;
    const int ac   = (tid & 7) * 4;

    int  arow_src[4]; bool avalid[4];
#pragma unroll
    for (int p = 0; p < 4; ++p) {
        int rg = m0g + p * 32 + ar;
        bool v = true;
        if (MODE == 1) v = ((rg & (Tt - 1)) >= m);
        avalid[p]   = v;
        arow_src[p] = (MODE >= 1 && v) ? (rg - m) : rg;
    }
    // A-write offsets (swizzled granule layout)
    int awo[4];
#pragma unroll
    for (int p = 0; p < 4; ++p) {
        int r = p * 32 + ar;
        awo[p] = r * 32 + ((((ac >> 3) ^ ((r >> 1) & 3))) << 3) + (ac & 7);
    }

    f32x4 acc[4][NJ];
#pragma unroll
    for (int i = 0; i < 4; ++i)
#pragma unroll
        for (int j = 0; j < NJ; ++j) acc[i][j] = (f32x4){0.f, 0.f, 0.f, 0.f};

    int a_off[4];
#pragma unroll
    for (int i = 0; i < 4; ++i) {
        int rl = wm0 + i * 16 + ln;
        a_off[i] = rl * 32 + (((lane >> 4) ^ ((rl >> 1) & 3)) << 3);
    }
    const int nlb    = wn0 + ln;
    const int b_off0 = BBASE + nlb * 32 +
                       (((lane >> 4) ^ ((nlb >> 1) & 3)) << 3);

    for (int kt = 0; kt < 32; ++kt) {
        __syncthreads();   // previous tile's ds_reads complete
        // ---- stage A: global fp32 -> bf16 (hi [+lo]) -> LDS ----
#pragma unroll
        for (int p = 0; p < 4; ++p) {
            float4 v = *reinterpret_cast<const float4*>(
                &Af[(size_t)arow_src[p] * Dd + kt * 32 + ac]);
            if (MODE == 1 && !avalid[p]) v = make_float4(0.f, 0.f, 0.f, 0.f);
            unsigned short h0 = f2bf_rne(v.x), h1 = f2bf_rne(v.y),
                           h2 = f2bf_rne(v.z), h3 = f2bf_rne(v.w);
            uint2 hw;
            hw.x = (unsigned)h0 | ((unsigned)h1 << 16);
            hw.y = (unsigned)h2 | ((unsigned)h3 << 16);
            *reinterpret_cast<uint2*>(&lds[awo[p]]) = hw;
            if (S3) {
                unsigned short g0 = f2bf_rne(v.x - bf2f(h0)),
                               g1 = f2bf_rne(v.y - bf2f(h1)),
                               g2 = f2bf_rne(v.z - bf2f(h2)),
                               g3 = f2bf_rne(v.w - bf2f(h3));
                uint2 lw;
                lw.x = (unsigned)g0 | ((unsigned)g1 << 16);
                lw.y = (unsigned)g2 | ((unsigned)g3 << 16);
                *reinterpret_cast<uint2*>(&lds[awo[p] + APL]) = lw;
            }
        }
        // ---- stage B: async DMA from pre-split swizzled layout ----
#pragma unroll
        for (int q = 0; q < (NT > 64 ? NT / 64 : 1); ++q) {
            int nidx = (NT >= 64) ? (q * 64 + (tid >> 2)) : 0;
            size_t gfo = ((size_t)(kt * 1024 + n0 + nidx) * 4 + (tid & 3)) * 8;
            dma16(&Bth[gfo], &lds[BBASE + q * 2048 + w * 512]);
            if (S3)
                dma16(&Btl[gfo], &lds[BBASE + BPL + q * 2048 + w * 512]);
        }
        __syncthreads();   // drains vmcnt (DMA) + lgkm (A writes)
        // ---- compute ----
        bf16x8 ah[4], al[4];
#pragma unroll
        for (int i = 0; i < 4; ++i) {
            ah[i] = *reinterpret_cast<const bf16x8*>(&lds[a_off[i]]);
            if (S3)
                al[i] = *reinterpret_cast<const bf16x8*>(&lds[a_off[i] + APL]);
        }
#pragma unroll
        for (int j = 0; j < NJ; ++j) {
            const bf16x8 bh = *reinterpret_cast<const bf16x8*>(
                &lds[b_off0 + j * 512]);
#pragma unroll
            for (int i = 0; i < 4; ++i)
                acc[i][j] = __builtin_amdgcn_mfma_f32_16x16x32_bf16(
                    ah[i], bh, acc[i][j], 0, 0, 0);
            if (S3) {
                const bf16x8 bl = *reinterpret_cast<const bf16x8*>(
                    &lds[b_off0 + j * 512 + BPL]);
#pragma unroll
                for (int i = 0; i < 4; ++i) {
                    acc[i][j] = __builtin_amdgcn_mfma_f32_16x16x32_bf16(
                        ah[i], bl, acc[i][j], 0, 0, 0);
                    acc[i][j] = __builtin_amdgcn_mfma_f32_16x16x32_bf16(
                        al[i], bh, acc[i][j], 0, 0, 0);
                }
            }
        }
    }

    // ---- epilogue ----
#pragma unroll
    for (int j = 0; j < NJ; ++j) {
        int cl  = wn0 + j * 16 + ln;
        int col = n0 + cl;
        float bj = (MODE == 0 && bias) ? bias[col] : 0.f;
#pragma unroll
        for (int i = 0; i < 4; ++i) {
            int rbase = m0g + wm0 + i * 16 + (lane >> 4) * 4;
            float vv[4];
#pragma unroll
            for (int e = 0; e < 4; ++e) {
                size_t off = (size_t)(rbase + e) * Dd + col;
                float v = acc[i][j][e] + bj;
                if (MODE >= 1) v += Sin[off];
                Cf[off] = v;
                vv[e] = v;
            }
            if (WSPLIT) {
                unsigned short h0 = f2bf_rne(vv[0]), h1 = f2bf_rne(vv[1]),
                               h2 = f2bf_rne(vv[2]), h3 = f2bf_rne(vv[3]);
                unsigned short l0 = f2bf_rne(vv[0] - bf2f(h0)),
                               l1 = f2bf_rne(vv[1] - bf2f(h1)),
                               l2 = f2bf_rne(vv[2] - bf2f(h2)),
                               l3 = f2bf_rne(vv[3] - bf2f(h3));
                uint2 hw, lw;
                hw.x = (unsigned)h0 | ((unsigned)h1 << 16);
                hw.y = (unsigned)h2 | ((unsigned)h3 << 16);
                lw.x = (unsigned)l0 | ((unsigned)l1 << 16);
                lw.y = (unsigned)l2 | ((unsigned)l3 << 16);
                int kt2 = rbase >> 5;
                int sl  = (rbase >> 3) & 3;
                int e0  = rbase & 7;
                size_t so = ((size_t)(kt2 * 1024 + col) * 4 +
                             (sl ^ ((col >> 1) & 3))) * 8 + e0;
                *reinterpret_cast<uint2*>(&Woh[so]) = hw;
                *reinterpret_cast<uint2*>(&Wol[so]) = lw;
            }
        }
    }
}

// ---------------------------------------------------------------------------
template<int MODE, int NT, int S3>
__global__ __launch_bounds__(256, 2)
void mfma_gemm(const float* __restrict__ Af,
               const short* __restrict__ Bth, const short* __restrict__ Btl,
               const float* __restrict__ bias,
               const float* __restrict__ Sin,
               float* __restrict__ Cf,
               int m, int tstart)
{
    constexpr int LSZ = (S3 ? 2 : 1) * (4096 + NT * 32);
    __shared__ __align__(16) short lds[LSZ];
    gemm_body<MODE, NT, S3, 0>(lds, blockIdx.x, blockIdx.y,
                               Af, Bth, Btl, bias, Sin, Cf,
                               nullptr, nullptr, m, tstart);
}

// ---------------------------------------------------------------------------
// Fused [scan level (1024 blocks, NT=256) + power squaring (64 blocks,
// NT=128, WSPLIT)] launch. Squares occupy by<16 (dispatch first).
// LDS 49152 B -> 3 blocks/CU headroom.
// ---------------------------------------------------------------------------
__global__ __launch_bounds__(256, 2)
void fused_ls(const float* __restrict__ Sfrom, float* __restrict__ Sto,
              const float* __restrict__ Pfrom, float* __restrict__ Pto,
              const short* __restrict__ Bqh, const short* __restrict__ Bql,
              short* __restrict__ Bqoh, short* __restrict__ Bqol,
              int m)
{
    __shared__ __align__(16) short lds[2 * (4096 + 8192)];
    if (blockIdx.y < 16) {
        int sq  = blockIdx.y;
        int sbx = blockIdx.x + ((sq & 1) << 2);
        int sby = sq >> 1;
        gemm_body<0, 128, 1, 1>(lds, sbx, sby, Pfrom, Bqh, Bql,
                                nullptr, nullptr, Pto, Bqoh, Bqol, 0, 0);
    } else {
        gemm_body<1, 256, 1, 0>(lds, blockIdx.x, blockIdx.y - 16,
                                Sfrom, Bqh, Bql, nullptr, Sfrom, Sto,
                                nullptr, nullptr, m, 0);
    }
}

// ---------------------------------------------------------------------------
// MLP GEMM: 512 thr, 128x256, bf16 hi-only, fused BN partials. A plane
// compacted to the swizzled 32-short layout (LDS 24576 B).
// ---------------------------------------------------------------------------
__global__ __launch_bounds__(512, 2)
void mlp_gemm(const float* __restrict__ Af,
              const short* __restrict__ Bth,
              const float* __restrict__ bias,
              float* __restrict__ Cf,
              float* __restrict__ psum, float* __restrict__ psq)
{
    constexpr int APL = 4096;
    constexpr int BB  = APL;
    __shared__ __align__(16) short lds[APL + 8192];

    const int tid  = threadIdx.x;
    const int lane = tid & 63;
    const int w    = tid >> 6;
    const int n0   = blockIdx.x * 256;
    const int m0g  = blockIdx.y * 128;
    const int wm0  = (w >> 2) * 64;
    const int wn0  = (w & 3) * 64;
    const int ln   = lane & 15;
    const int ar   = tid >> 2;          // 0..127 (A row)
    const int ac   = (tid & 3) * 8;     // 0,8,16,24 (full granule)
    const int awo  = ar * 32 + ((((ac >> 3) ^ ((ar >> 1) & 3))) << 3);

    f32x4 acc[4][4];
#pragma unroll
    for (int i = 0; i < 4; ++i)
#pragma unroll
        for (int j = 0; j < 4; ++j) acc[i][j] = (f32x4){0.f, 0.f, 0.f, 0.f};

    int a_off[4];
#pragma unroll
    for (int i = 0; i < 4; ++i) {
        int rl = wm0 + i * 16 + ln;
        a_off[i] = rl * 32 + (((lane >> 4) ^ ((rl >> 1) & 3)) << 3);
    }
    const int nlb    = wn0 + ln;
    const int b_off0 = BB + nlb * 32 +
                       (((lane >> 4) ^ ((nlb >> 1) & 3)) << 3);

    for (int kt = 0; kt < 32; ++kt) {
        __syncthreads();
        {
            const float* p = &Af[(size_t)(m0g + ar) * Dd + kt * 32 + ac];
            float4 v0 = *reinterpret_cast<const float4*>(p);
            float4 v1 = *reinterpret_cast<const float4*>(p + 4);
            unsigned short h0 = f2bf_rne(v0.x), h1 = f2bf_rne(v0.y),
                           h2 = f2bf_rne(v0.z), h3 = f2bf_rne(v0.w),
                           h4 = f2bf_rne(v1.x), h5 = f2bf_rne(v1.y),
                           h6 = f2bf_rne(v1.z), h7 = f2bf_rne(v1.w);
            int4 hw;
            hw.x = (int)((unsigned)h0 | ((unsigned)h1 << 16));
            hw.y = (int)((unsigned)h2 | ((unsigned)h3 << 16));
            hw.z = (int)((unsigned)h4 | ((unsigned)h5 << 16));
            hw.w = (int)((unsigned)h6 | ((unsigned)h7 << 16));
            *reinterpret_cast<int4*>(&lds[awo]) = hw;
        }
#pragma unroll
        for (int q = 0; q < 2; ++q) {
            size_t gfo = ((size_t)(kt * 1024 + n0 + q * 128 + (tid >> 2))
                          * 4 + (tid & 3)) * 8;
            dma16(&Bth[gfo], &lds[BB + q * 4096 + w * 512]);
        }
        __syncthreads();
        bf16x8 ah[4];
#pragma unroll
        for (int i = 0; i < 4; ++i)
            ah[i] = *reinterpret_cast<const bf16x8*>(&lds[a_off[i]]);
#pragma unroll
        for (int j = 0; j < 4; ++j) {
            const bf16x8 bh = *reinterpret_cast<const bf16x8*>(
                &lds[b_off0 + j * 512]);
#pragma unroll
            for (int i = 0; i < 4; ++i)
                acc[i][j] = __builtin_amdgcn_mfma_f32_16x16x32_bf16(
                    ah[i], bh, acc[i][j], 0, 0, 0);
        }
    }

    float* bnF = reinterpret_cast<float*>(lds);
    __syncthreads();
    if (tid < 256) { bnF[tid] = 0.f; bnF[256 + tid] = 0.f; }
    __syncthreads();
#pragma unroll
    for (int j = 0; j < 4; ++j) {
        int cl  = wn0 + j * 16 + ln;
        int col = n0 + cl;
        float bj = bias[col];
        float sv = 0.f, sq = 0.f;
#pragma unroll
        for (int i = 0; i < 4; ++i) {
            int rbase = m0g + wm0 + i * 16 + (lane >> 4) * 4;
#pragma unroll
            for (int e = 0; e < 4; ++e) {
                size_t off = (size_t)(rbase + e) * Dd + col;
                float v = acc[i][j][e] + bj;
                Cf[off] = v;
                sv += v; sq += v * v;
            }
        }
        atomicAdd(&bnF[cl], sv); atomicAdd(&bnF[256 + cl], sq);
    }
    __syncthreads();
    if (tid < 256) {
        psum[(size_t)blockIdx.y * Dd + n0 + tid] = bnF[tid];
        psq [(size_t)blockIdx.y * Dd + n0 + tid] = bnF[256 + tid];
    }
}

// ---------------------------------------------------------------------------
__global__ __launch_bounds__(256)
void bn_stats(const float* __restrict__ ps, const float* __restrict__ pq,
              const float* __restrict__ scale, const float* __restrict__ bias,
              float* __restrict__ Av, float* __restrict__ Cv)
{
    const int d = blockIdx.x * 256 + threadIdx.x;
    float s = 0.f, q = 0.f;
    for (int p = 0; p < 256; ++p) {
        s += ps[p * Dd + d];
        q += pq[p * Dd + d];
    }
    const float invN = 1.0f / 32768.0f;
    float mean = s * invN;
    float var  = q * invN - mean * mean;
    float rs   = rsqrtf(var + 1e-5f);
    float a    = rs * scale[d];
    Av[d] = a;
    Cv[d] = bias[d] - mean * a;
}

// ---------------------------------------------------------------------------
__global__ __launch_bounds__(256)
void residual_gelu(const float* __restrict__ Z, const float* __restrict__ Yin,
                   float* __restrict__ Yout,
                   const float* __restrict__ Av, const float* __restrict__ Cv)
{
    const float4* z4 = reinterpret_cast<const float4*>(Z);
    const float4* y4 = reinterpret_cast<const float4*>(Yin);
    float4*       o4 = reinterpret_cast<float4*>(Yout);
    const float4* a4 = reinterpret_cast<const float4*>(Av);
    const float4* c4 = reinterpret_cast<const float4*>(Cv);
    const int n4 = MTOT * Dd / 4;
    for (int i = blockIdx.x * blockDim.x + threadIdx.x; i < n4;
         i += gridDim.x * blockDim.x) {
        int d4 = i & (Dd / 4 - 1);
        float4 z = z4[i], y = y4[i], a = a4[d4], c = c4[d4];
        float4 o;
        o.x = gelu_tanh(fmaf(z.x, a.x, c.x)) + y.x;
        o.y = gelu_tanh(fmaf(z.y, a.y, c.y)) + y.y;
        o.z = gelu_tanh(fmaf(z.z, a.z, c.z)) + y.z;
        o.w = gelu_tanh(fmaf(z.w, a.w, c.w)) + y.w;
        o4[i] = o;
    }
}

// ---------------------------------------------------------------------------
extern "C" void kernel_launch(void* const* d_in, const int* in_sizes, int n_in,
                              void* d_out, int out_size, void* d_ws, size_t ws_size,
                              hipStream_t stream)
{
    const float* x    = (const float*)d_in[0];
    const float* Wi   = (const float*)d_in[1];
    const float* bi   = (const float*)d_in[2];
    const float* Wh   = (const float*)d_in[3];
    const float* mlpW = (const float*)d_in[4];
    const float* mlpb = (const float*)d_in[5];
    const float* bns  = (const float*)d_in[6];
    const float* bnb  = (const float*)d_in[7];
    float* out = (float*)d_out;

    const size_t NE = (size_t)MTOT * Dd;
    const size_t MM = (size_t)Dd * Dd;       // 1M
    float* ws   = (float*)d_ws;
    float* S0   = ws;                        // 32M floats (128 MiB)
    float* Pa   = S0 + NE;
    float* Pb   = Pa + MM;
    float* psum = Pb + MM;                   // [256][1024]
    float* psq  = psum + 256 * Dd;
    float* abuf = psq + 256 * Dd;
    float* cbuf = abuf + Dd;
    short* Bq0h = (short*)(cbuf + Dd);       // split buffers, 1M shorts each
    short* Bq0l = Bq0h + MM;
    short* Bq1h = Bq0l + MM;
    short* Bq1l = Bq1h + MM;
    short* BmH[NL]; short* BmL[NL];
    {
        short* p = Bq1l + MM;
        for (int l = 0; l < NL; ++l) { BmH[l] = p; p += MM; BmL[l] = p; p += MM; }
    }

    const dim3 gBig(4, 256);    // 128x256 tiles, 256 thr
    const dim3 gF  (4, 272);    // fused: 16 square-rows + 256 level-rows
    const dim3 gSeq(16, 16);    // carries: 128x64 tiles (256 blocks, all CUs)
    const dim3 gBt (32, 32);

    // ---- all input-matrix splits upfront ----
    split_bt<<<gBt, 256, 0, stream>>>(Wi, Bq0h, Bq0l);
    split_bt<<<gBt, 256, 0, stream>>>(Wh, Bq1h, Bq1l);
    for (int l = 0; l < NL; ++l)
        split_bt<<<gBt, 256, 0, stream>>>(mlpW + (size_t)l * MM, BmH[l], BmL[l]);

    // ---- Phase 1: xp = x @ Wi + bi -> S0 ----
    mfma_gemm<0, 256, 1><<<gBig, 256, 0, stream>>>(
        x, Bq0h, Bq0l, bi, nullptr, S0, 0, 0);

    // ---- Phase 2: 7 fused [level + squaring] launches ----
    fused_ls<<<gF, 256, 0, stream>>>(S0, out, Wh, Pa, Bq1h, Bq1l, Bq0h, Bq0l, 1);
    fused_ls<<<gF, 256, 0, stream>>>(out, S0, Pa, Pb, Bq0h, Bq0l, Bq1h, Bq1l, 2);
    fused_ls<<<gF, 256, 0, stream>>>(S0, out, Pb, Pa, Bq1h, Bq1l, Bq0h, Bq0l, 4);
    fused_ls<<<gF, 256, 0, stream>>>(out, S0, Pa, Pb, Bq0h, Bq0l, Bq1h, Bq1l, 8);
    fused_ls<<<gF, 256, 0, stream>>>(S0, out, Pb, Pa, Bq1h, Bq1l, Bq0h, Bq0l, 16);
    fused_ls<<<gF, 256, 0, stream>>>(out, S0, Pa, Pb, Bq0h, Bq0l, Bq1h, Bq1l, 32);
    fused_ls<<<gF, 256, 0, stream>>>(S0, out, Pb, Pa, Bq1h, Bq1l, Bq0h, Bq0l, 64);
    // state now in `out`; split(P128) now in Bq0.

    // ---- Phase 3: 15 sequential carry steps with P128 (in-place on out),
    //      NT=64 tiles -> 256 blocks = every CU busy ----
    for (int i = 1; i < 16; ++i)
        mfma_gemm<2, 64, 1><<<gSeq, 256, 0, stream>>>(
            out, Bq0h, Bq0l, nullptr, out, out, 128, 128 * i);

    // ---- Phase 4: residual MLP stack (512-thr bf16 GEMMs); y in out, z->S0 ----
    for (int l = 0; l < NL; ++l) {
        mlp_gemm<<<gBig, 512, 0, stream>>>(
            out, BmH[l], mlpb + (size_t)l * Dd, S0, psum, psq);
        bn_stats<<<4, 256, 0, stream>>>(psum, psq, bns + (size_t)l * Dd,
                                        bnb + (size_t)l * Dd, abuf, cbuf);
        residual_gelu<<<2048, 256, 0, stream>>>(S0, out, out, abuf, cbuf);
    }
}

// Round 19
// 3388.834 us; speedup vs baseline: 1.3276x; 1.0413x over previous
//
#include <hip/hip_runtime.h>
#include <math.h>

#define Bb   16
#define Tt   2048
#define Dd   1024
#define NL   4
#define MTOT (Bb * Tt)   // 32768

typedef float f32x4 __attribute__((ext_vector_type(4)));
typedef short bf16x8 __attribute__((ext_vector_type(8)));

// ---------------------------------------------------------------------------
__device__ __forceinline__ unsigned short f2bf_rne(float x) {
    unsigned u = __float_as_uint(x);
    u += 0x7fffu + ((u >> 16) & 1u);
    return (unsigned short)(u >> 16);
}
__device__ __forceinline__ float bf2f(unsigned short h) {
    return __uint_as_float(((unsigned)h) << 16);
}
__device__ __forceinline__ float gelu_tanh(float x) {
    float x3 = x * x * x;
    float u  = 0.7978845608028654f * (x + 0.044715f * x3);
    return 0.5f * x * (1.0f + tanhf(u));
}
// async 16B global -> LDS (HW: wave-uniform LDS base + lane*16)
__device__ __forceinline__ void dma16(const void* g, void* l) {
    __builtin_amdgcn_global_load_lds(
        (const __attribute__((address_space(1))) unsigned int*)g,
        (__attribute__((address_space(3))) unsigned int*)l, 16, 0, 0);
}
// XCD-aware remap for 1024-block (4 n x 256 m) grids: the 4 n-blocks of an
// m-tile get bids {g*32+j*8+x} == x (mod 8) -> same XCD L2 holds the A/Sin
// panel; concurrent by' form contiguous 8-tile bands (write-local).
__device__ __forceinline__ void xcd_remap(int lbid, int& bx, int& by) {
    by = (lbid >> 5) * 8 + (lbid & 7);
    bx = (lbid >> 3) & 3;
}

// ---------------------------------------------------------------------------
// Split a [1024,1024] fp32 matrix (row-major [k][n]) into bf16 hi/lo with
// k-tiled, slot-swizzled layout (proven R6 B-path):
//   element (k,n): kt=k>>5, sl=(k>>3)&3, e=k&7
//   shorts offset = ((kt*1024+n)*4 + (sl^((n>>1)&3)))*8 + e
// ---------------------------------------------------------------------------
__global__ __launch_bounds__(256)
void split_bt(const float* __restrict__ B, short* __restrict__ ht,
              short* __restrict__ lt)
{
    __shared__ float tile[32][33];
    const int t  = threadIdx.x;
    const int r  = t >> 3;          // 0..31
    const int c  = (t & 7) * 4;     // 0,4,...,28
    const int kb = blockIdx.y * 32; // kt = blockIdx.y
    const int nb = blockIdx.x * 32;
    float4 v = *reinterpret_cast<const float4*>(
        &B[(size_t)(kb + r) * Dd + nb + c]);
    tile[r][c + 0] = v.x; tile[r][c + 1] = v.y;
    tile[r][c + 2] = v.z; tile[r][c + 3] = v.w;
    __syncthreads();
    unsigned h[4], lo[4];
#pragma unroll
    for (int q = 0; q < 4; ++q) {
        float f = tile[c + q][r];           // B[kb+c+q][nb+r]
        unsigned short hh = f2bf_rne(f);
        float rem = f - bf2f(hh);
        h[q]  = hh;
        lo[q] = f2bf_rne(rem);
    }
    uint2 hw, lw;
    hw.x = h[0]  | (h[1]  << 16); hw.y = h[2]  | (h[3]  << 16);
    lw.x = lo[0] | (lo[1] << 16); lw.y = lo[2] | (lo[3] << 16);
    const int n = nb + r;
    const int s = (c >> 3) ^ ((n >> 1) & 3);   // swizzled slot
    size_t off = ((size_t)(blockIdx.y * 1024 + n) * 4 + s) * 8 + (c & 4);
    *reinterpret_cast<uint2*>(&ht[off]) = hw;
    *reinterpret_cast<uint2*>(&lt[off]) = lw;
}

// ---------------------------------------------------------------------------
// R6-proven split-precision MFMA GEMM body (device function, inlined).
// Tile 128xNT, BK=32, 256 thr = 4 waves (2x2), two barriers per k-tile.
// A planes use the 32-short XOR-swizzled granule layout (R18, conflict-free).
// S3=1: split precision (hi+lo planes, 3 MFMA). S3=0: bf16 hi-only (1 MFMA).
// MODE 0: C = A@B (+bias); MODE 1: C[t]=Sin[t]+(t%Tt>=m ? A[t-m]@B : 0);
// MODE 2: rows [tstart,tstart+128) per batch: C[r]=Sin[r]+A[r-128]@B.
// WSPLIT=1: epilogue also writes C into the split/swizzled B-layout.
// ---------------------------------------------------------------------------
template<int MODE, int NT, int S3, int WSPLIT>
__device__ __forceinline__ void gemm_body(
    short* lds, int bx, int by,
    const float* __restrict__ Af,
    const short* __restrict__ Bth, const short* __restrict__ Btl,
    const float* __restrict__ bias,
    const float* __restrict__ Sin,
    float* __restrict__ Cf,
    short* __restrict__ Woh, short* __restrict__ Wol,
    int m, int tstart)
{
    constexpr int NJ    = NT / 32;
    constexpr int APL   = 4096;              // shorts per A plane (128*32)
    constexpr int BBASE = (S3 ? 2 : 1) * APL;
    constexpr int BPL   = NT * 32;           // shorts per B plane

    const int tid  = threadIdx.x;
    const int lane = tid & 63;
    const int w    = tid >> 6;
    const int n0   = bx * NT;
    const int m0g  = (MODE == 2) ? (by * Tt + tstart) : (by * 128);
    const int wm0  = (w >> 1) * 64;
    const int wn0  = (w & 1) * (NT / 2);
    const int ln   = lane & 15;
    const int ar   = tid >> 3;
    const int ac   = (tid & 7) * 4;

    int  arow_src[4]; bool avalid[4];
#pragma unroll
    for (int p = 0; p < 4; ++p) {
        int rg = m0g + p * 32 + ar;
        bool v = true;
        if (MODE == 1) v = ((rg & (Tt - 1)) >= m);
        avalid[p]   = v;
        arow_src[p] = (MODE >= 1 && v) ? (rg - m) : rg;
    }
    // A-write offsets (swizzled granule layout)
    int awo[4];
#pragma unroll
    for (int p = 0; p < 4; ++p) {
        int r = p * 32 + ar;
        awo[p] = r * 32 + ((((ac >> 3) ^ ((r >> 1) & 3))) << 3) + (ac & 7);
    }

    f32x4 acc[4][NJ];
#pragma unroll
    for (int i = 0; i < 4; ++i)
#pragma unroll
        for (int j = 0; j < NJ; ++j) acc[i][j] = (f32x4){0.f, 0.f, 0.f, 0.f};

    int a_off[4];
#pragma unroll
    for (int i = 0; i < 4; ++i) {
        int rl = wm0 + i * 16 + ln;
        a_off[i] = rl * 32 + (((lane >> 4) ^ ((rl >> 1) & 3)) << 3);
    }
    const int nlb    = wn0 + ln;
    const int b_off0 = BBASE + nlb * 32 +
                       (((lane >> 4) ^ ((nlb >> 1) & 3)) << 3);

    for (int kt = 0; kt < 32; ++kt) {
        __syncthreads();   // previous tile's ds_reads complete
        // ---- stage A: global fp32 -> bf16 (hi [+lo]) -> LDS ----
#pragma unroll
        for (int p = 0; p < 4; ++p) {
            float4 v = *reinterpret_cast<const float4*>(
                &Af[(size_t)arow_src[p] * Dd + kt * 32 + ac]);
            if (MODE == 1 && !avalid[p]) v = make_float4(0.f, 0.f, 0.f, 0.f);
            unsigned short h0 = f2bf_rne(v.x), h1 = f2bf_rne(v.y),
                           h2 = f2bf_rne(v.z), h3 = f2bf_rne(v.w);
            uint2 hw;
            hw.x = (unsigned)h0 | ((unsigned)h1 << 16);
            hw.y = (unsigned)h2 | ((unsigned)h3 << 16);
            *reinterpret_cast<uint2*>(&lds[awo[p]]) = hw;
            if (S3) {
                unsigned short g0 = f2bf_rne(v.x - bf2f(h0)),
                               g1 = f2bf_rne(v.y - bf2f(h1)),
                               g2 = f2bf_rne(v.z - bf2f(h2)),
                               g3 = f2bf_rne(v.w - bf2f(h3));
                uint2 lw;
                lw.x = (unsigned)g0 | ((unsigned)g1 << 16);
                lw.y = (unsigned)g2 | ((unsigned)g3 << 16);
                *reinterpret_cast<uint2*>(&lds[awo[p] + APL]) = lw;
            }
        }
        // ---- stage B: async DMA from pre-split swizzled layout ----
#pragma unroll
        for (int q = 0; q < (NT > 64 ? NT / 64 : 1); ++q) {
            int nidx = (NT >= 64) ? (q * 64 + (tid >> 2)) : 0;
            size_t gfo = ((size_t)(kt * 1024 + n0 + nidx) * 4 + (tid & 3)) * 8;
            dma16(&Bth[gfo], &lds[BBASE + q * 2048 + w * 512]);
            if (S3)
                dma16(&Btl[gfo], &lds[BBASE + BPL + q * 2048 + w * 512]);
        }
        __syncthreads();   // drains vmcnt (DMA) + lgkm (A writes)
        // ---- compute ----
        bf16x8 ah[4], al[4];
#pragma unroll
        for (int i = 0; i < 4; ++i) {
            ah[i] = *reinterpret_cast<const bf16x8*>(&lds[a_off[i]]);
            if (S3)
                al[i] = *reinterpret_cast<const bf16x8*>(&lds[a_off[i] + APL]);
        }
#pragma unroll
        for (int j = 0; j < NJ; ++j) {
            const bf16x8 bh = *reinterpret_cast<const bf16x8*>(
                &lds[b_off0 + j * 512]);
#pragma unroll
            for (int i = 0; i < 4; ++i)
                acc[i][j] = __builtin_amdgcn_mfma_f32_16x16x32_bf16(
                    ah[i], bh, acc[i][j], 0, 0, 0);
            if (S3) {
                const bf16x8 bl = *reinterpret_cast<const bf16x8*>(
                    &lds[b_off0 + j * 512 + BPL]);
#pragma unroll
                for (int i = 0; i < 4; ++i) {
                    acc[i][j] = __builtin_amdgcn_mfma_f32_16x16x32_bf16(
                        ah[i], bl, acc[i][j], 0, 0, 0);
                    acc[i][j] = __builtin_amdgcn_mfma_f32_16x16x32_bf16(
                        al[i], bh, acc[i][j], 0, 0, 0);
                }
            }
        }
    }

    // ---- epilogue ----
#pragma unroll
    for (int j = 0; j < NJ; ++j) {
        int cl  = wn0 + j * 16 + ln;
        int col = n0 + cl;
        float bj = (MODE == 0 && bias) ? bias[col] : 0.f;
#pragma unroll
        for (int i = 0; i < 4; ++i) {
            int rbase = m0g + wm0 + i * 16 + (lane >> 4) * 4;
            float vv[4];
#pragma unroll
            for (int e = 0; e < 4; ++e) {
                size_t off = (size_t)(rbase + e) * Dd + col;
                float v = acc[i][j][e] + bj;
                if (MODE >= 1) v += Sin[off];
                Cf[off] = v;
                vv[e] = v;
            }
            if (WSPLIT) {
                unsigned short h0 = f2bf_rne(vv[0]), h1 = f2bf_rne(vv[1]),
                               h2 = f2bf_rne(vv[2]), h3 = f2bf_rne(vv[3]);
                unsigned short l0 = f2bf_rne(vv[0] - bf2f(h0)),
                               l1 = f2bf_rne(vv[1] - bf2f(h1)),
                               l2 = f2bf_rne(vv[2] - bf2f(h2)),
                               l3 = f2bf_rne(vv[3] - bf2f(h3));
                uint2 hw, lw;
                hw.x = (unsigned)h0 | ((unsigned)h1 << 16);
                hw.y = (unsigned)h2 | ((unsigned)h3 << 16);
                lw.x = (unsigned)l0 | ((unsigned)l1 << 16);
                lw.y = (unsigned)l2 | ((unsigned)l3 << 16);
                int kt2 = rbase >> 5;
                int sl  = (rbase >> 3) & 3;
                int e0  = rbase & 7;
                size_t so = ((size_t)(kt2 * 1024 + col) * 4 +
                             (sl ^ ((col >> 1) & 3))) * 8 + e0;
                *reinterpret_cast<uint2*>(&Woh[so]) = hw;
                *reinterpret_cast<uint2*>(&Wol[so]) = lw;
            }
        }
    }
}

// ---------------------------------------------------------------------------
// REMAP=1 applies the XCD-aware bijection (grids with 4 x 256 logical tiles).
template<int MODE, int NT, int S3, int REMAP>
__global__ __launch_bounds__(256, 2)
void mfma_gemm(const float* __restrict__ Af,
               const short* __restrict__ Bth, const short* __restrict__ Btl,
               const float* __restrict__ bias,
               const float* __restrict__ Sin,
               float* __restrict__ Cf,
               int m, int tstart)
{
    constexpr int LSZ = (S3 ? 2 : 1) * (4096 + NT * 32);
    __shared__ __align__(16) short lds[LSZ];
    int bx = blockIdx.x, by = blockIdx.y;
    if (REMAP) xcd_remap(blockIdx.y * gridDim.x + blockIdx.x, bx, by);
    gemm_body<MODE, NT, S3, 0>(lds, bx, by,
                               Af, Bth, Btl, bias, Sin, Cf,
                               nullptr, nullptr, m, tstart);
}

// ---------------------------------------------------------------------------
// Fused [scan level (1024 blocks, NT=256, XCD-remapped) + power squaring
// (64 blocks, NT=128, WSPLIT)] launch. Squares occupy by<16 (dispatch first).
// ---------------------------------------------------------------------------
__global__ __launch_bounds__(256, 2)
void fused_ls(const float* __restrict__ Sfrom, float* __restrict__ Sto,
              const float* __restrict__ Pfrom, float* __restrict__ Pto,
              const short* __restrict__ Bqh, const short* __restrict__ Bql,
              short* __restrict__ Bqoh, short* __restrict__ Bqol,
              int m)
{
    __shared__ __align__(16) short lds[2 * (4096 + 8192)];
    if (blockIdx.y < 16) {
        int sq  = blockIdx.y;
        int sbx = blockIdx.x + ((sq & 1) << 2);
        int sby = sq >> 1;
        gemm_body<0, 128, 1, 1>(lds, sbx, sby, Pfrom, Bqh, Bql,
                                nullptr, nullptr, Pto, Bqoh, Bqol, 0, 0);
    } else {
        int lbid = (blockIdx.y - 16) * 4 + blockIdx.x;  // xcd = lbid%8 (64==0 mod 8)
        int bx, by;
        xcd_remap(lbid, bx, by);
        gemm_body<1, 256, 1, 0>(lds, bx, by,
                                Sfrom, Bqh, Bql, nullptr, Sfrom, Sto,
                                nullptr, nullptr, m, 0);
    }
}

// ---------------------------------------------------------------------------
// MLP GEMM: 512 thr, 128x256, bf16 hi-only, fused BN partials, XCD-remapped.
// ---------------------------------------------------------------------------
__global__ __launch_bounds__(512, 2)
void mlp_gemm(const float* __restrict__ Af,
              const short* __restrict__ Bth,
              const float* __restrict__ bias,
              float* __restrict__ Cf,
              float* __restrict__ psum, float* __restrict__ psq)
{
    constexpr int APL = 4096;
    constexpr int BB  = APL;
    __shared__ __align__(16) short lds[APL + 8192];

    int bxr, byr;
    xcd_remap(blockIdx.y * gridDim.x + blockIdx.x, bxr, byr);

    const int tid  = threadIdx.x;
    const int lane = tid & 63;
    const int w    = tid >> 6;
    const int n0   = bxr * 256;
    const int m0g  = byr * 128;
    const int wm0  = (w >> 2) * 64;
    const int wn0  = (w & 3) * 64;
    const int ln   = lane & 15;
    const int ar   = tid >> 2;          // 0..127 (A row)
    const int ac   = (tid & 3) * 8;     // 0,8,16,24 (full granule)
    const int awo  = ar * 32 + ((((ac >> 3) ^ ((ar >> 1) & 3))) << 3);

    f32x4 acc[4][4];
#pragma unroll
    for (int i = 0; i < 4; ++i)
#pragma unroll
        for (int j = 0; j < 4; ++j) acc[i][j] = (f32x4){0.f, 0.f, 0.f, 0.f};

    int a_off[4];
#pragma unroll
    for (int i = 0; i < 4; ++i) {
        int rl = wm0 + i * 16 + ln;
        a_off[i] = rl * 32 + (((lane >> 4) ^ ((rl >> 1) & 3)) << 3);
    }
    const int nlb    = wn0 + ln;
    const int b_off0 = BB + nlb * 32 +
                       (((lane >> 4) ^ ((nlb >> 1) & 3)) << 3);

    for (int kt = 0; kt < 32; ++kt) {
        __syncthreads();
        {
            const float* p = &Af[(size_t)(m0g + ar) * Dd + kt * 32 + ac];
            float4 v0 = *reinterpret_cast<const float4*>(p);
            float4 v1 = *reinterpret_cast<const float4*>(p + 4);
            unsigned short h0 = f2bf_rne(v0.x), h1 = f2bf_rne(v0.y),
                           h2 = f2bf_rne(v0.z), h3 = f2bf_rne(v0.w),
                           h4 = f2bf_rne(v1.x), h5 = f2bf_rne(v1.y),
                           h6 = f2bf_rne(v1.z), h7 = f2bf_rne(v1.w);
            int4 hw;
            hw.x = (int)((unsigned)h0 | ((unsigned)h1 << 16));
            hw.y = (int)((unsigned)h2 | ((unsigned)h3 << 16));
            hw.z = (int)((unsigned)h4 | ((unsigned)h5 << 16));
            hw.w = (int)((unsigned)h6 | ((unsigned)h7 << 16));
            *reinterpret_cast<int4*>(&lds[awo]) = hw;
        }
#pragma unroll
        for (int q = 0; q < 2; ++q) {
            size_t gfo = ((size_t)(kt * 1024 + n0 + q * 128 + (tid >> 2))
                          * 4 + (tid & 3)) * 8;
            dma16(&Bth[gfo], &lds[BB + q * 4096 + w * 512]);
        }
        __syncthreads();
        bf16x8 ah[4];
#pragma unroll
        for (int i = 0; i < 4; ++i)
            ah[i] = *reinterpret_cast<const bf16x8*>(&lds[a_off[i]]);
#pragma unroll
        for (int j = 0; j < 4; ++j) {
            const bf16x8 bh = *reinterpret_cast<const bf16x8*>(
                &lds[b_off0 + j * 512]);
#pragma unroll
            for (int i = 0; i < 4; ++i)
                acc[i][j] = __builtin_amdgcn_mfma_f32_16x16x32_bf16(
                    ah[i], bh, acc[i][j], 0, 0, 0);
        }
    }

    float* bnF = reinterpret_cast<float*>(lds);
    __syncthreads();
    if (tid < 256) { bnF[tid] = 0.f; bnF[256 + tid] = 0.f; }
    __syncthreads();
#pragma unroll
    for (int j = 0; j < 4; ++j) {
        int cl  = wn0 + j * 16 + ln;
        int col = n0 + cl;
        float bj = bias[col];
        float sv = 0.f, sq = 0.f;
#pragma unroll
        for (int i = 0; i < 4; ++i) {
            int rbase = m0g + wm0 + i * 16 + (lane >> 4) * 4;
#pragma unroll
            for (int e = 0; e < 4; ++e) {
                size_t off = (size_t)(rbase + e) * Dd + col;
                float v = acc[i][j][e] + bj;
                Cf[off] = v;
                sv += v; sq += v * v;
            }
        }
        atomicAdd(&bnF[cl], sv); atomicAdd(&bnF[256 + cl], sq);
    }
    __syncthreads();
    if (tid < 256) {
        psum[(size_t)byr * Dd + n0 + tid] = bnF[tid];
        psq [(size_t)byr * Dd + n0 + tid] = bnF[256 + tid];
    }
}

// ---------------------------------------------------------------------------
__global__ __launch_bounds__(256)
void bn_stats(const float* __restrict__ ps, const float* __restrict__ pq,
              const float* __restrict__ scale, const float* __restrict__ bias,
              float* __restrict__ Av, float* __restrict__ Cv)
{
    const int d = blockIdx.x * 256 + threadIdx.x;
    float s = 0.f, q = 0.f;
    for (int p = 0; p < 256; ++p) {
        s += ps[p * Dd + d];
        q += pq[p * Dd + d];
    }
    const float invN = 1.0f / 32768.0f;
    float mean = s * invN;
    float var  = q * invN - mean * mean;
    float rs   = rsqrtf(var + 1e-5f);
    float a    = rs * scale[d];
    Av[d] = a;
    Cv[d] = bias[d] - mean * a;
}

// ---------------------------------------------------------------------------
__global__ __launch_bounds__(256)
void residual_gelu(const float* __restrict__ Z, const float* __restrict__ Yin,
                   float* __restrict__ Yout,
                   const float* __restrict__ Av, const float* __restrict__ Cv)
{
    const float4* z4 = reinterpret_cast<const float4*>(Z);
    const float4* y4 = reinterpret_cast<const float4*>(Yin);
    float4*       o4 = reinterpret_cast<float4*>(Yout);
    const float4* a4 = reinterpret_cast<const float4*>(Av);
    const float4* c4 = reinterpret_cast<const float4*>(Cv);
    const int n4 = MTOT * Dd / 4;
    for (int i = blockIdx.x * blockDim.x + threadIdx.x; i < n4;
         i += gridDim.x * blockDim.x) {
        int d4 = i & (Dd / 4 - 1);
        float4 z = z4[i], y = y4[i], a = a4[d4], c = c4[d4];
        float4 o;
        o.x = gelu_tanh(fmaf(z.x, a.x, c.x)) + y.x;
        o.y = gelu_tanh(fmaf(z.y, a.y, c.y)) + y.y;
        o.z = gelu_tanh(fmaf(z.z, a.z, c.z)) + y.z;
        o.w = gelu_tanh(fmaf(z.w, a.w, c.w)) + y.w;
        o4[i] = o;
    }
}

// ---------------------------------------------------------------------------
extern "C" void kernel_launch(void* const* d_in, const int* in_sizes, int n_in,
                              void* d_out, int out_size, void* d_ws, size_t ws_size,
                              hipStream_t stream)
{
    const float* x    = (const float*)d_in[0];
    const float* Wi   = (const float*)d_in[1];
    const float* bi   = (const float*)d_in[2];
    const float* Wh   = (const float*)d_in[3];
    const float* mlpW = (const float*)d_in[4];
    const float* mlpb = (const float*)d_in[5];
    const float* bns  = (const float*)d_in[6];
    const float* bnb  = (const float*)d_in[7];
    float* out = (float*)d_out;

    const size_t NE = (size_t)MTOT * Dd;
    const size_t MM = (size_t)Dd * Dd;       // 1M
    float* ws   = (float*)d_ws;
    float* S0   = ws;                        // 32M floats (128 MiB)
    float* Pa   = S0 + NE;
    float* Pb   = Pa + MM;
    float* psum = Pb + MM;                   // [256][1024]
    float* psq  = psum + 256 * Dd;
    float* abuf = psq + 256 * Dd;
    float* cbuf = abuf + Dd;
    short* Bq0h = (short*)(cbuf + Dd);       // split buffers, 1M shorts each
    short* Bq0l = Bq0h + MM;
    short* Bq1h = Bq0l + MM;
    short* Bq1l = Bq1h + MM;
    short* BmH[NL]; short* BmL[NL];
    {
        short* p = Bq1l + MM;
        for (int l = 0; l < NL; ++l) { BmH[l] = p; p += MM; BmL[l] = p; p += MM; }
    }

    const dim3 gBig(4, 256);    // 128x256 tiles, 256 thr
    const dim3 gF  (4, 272);    // fused: 16 square-rows + 256 level-rows
    const dim3 gSeq(16, 16);    // carries: 128x64 tiles (256 blocks, all CUs)
    const dim3 gBt (32, 32);

    // ---- all input-matrix splits upfront ----
    split_bt<<<gBt, 256, 0, stream>>>(Wi, Bq0h, Bq0l);
    split_bt<<<gBt, 256, 0, stream>>>(Wh, Bq1h, Bq1l);
    for (int l = 0; l < NL; ++l)
        split_bt<<<gBt, 256, 0, stream>>>(mlpW + (size_t)l * MM, BmH[l], BmL[l]);

    // ---- Phase 1: xp = x @ Wi + bi -> S0 (XCD-remapped) ----
    mfma_gemm<0, 256, 1, 1><<<gBig, 256, 0, stream>>>(
        x, Bq0h, Bq0l, bi, nullptr, S0, 0, 0);

    // ---- Phase 2: 7 fused [level + squaring] launches ----
    fused_ls<<<gF, 256, 0, stream>>>(S0, out, Wh, Pa, Bq1h, Bq1l, Bq0h, Bq0l, 1);
    fused_ls<<<gF, 256, 0, stream>>>(out, S0, Pa, Pb, Bq0h, Bq0l, Bq1h, Bq1l, 2);
    fused_ls<<<gF, 256, 0, stream>>>(S0, out, Pb, Pa, Bq1h, Bq1l, Bq0h, Bq0l, 4);
    fused_ls<<<gF, 256, 0, stream>>>(out, S0, Pa, Pb, Bq0h, Bq0l, Bq1h, Bq1l, 8);
    fused_ls<<<gF, 256, 0, stream>>>(S0, out, Pb, Pa, Bq1h, Bq1l, Bq0h, Bq0l, 16);
    fused_ls<<<gF, 256, 0, stream>>>(out, S0, Pa, Pb, Bq0h, Bq0l, Bq1h, Bq1l, 32);
    fused_ls<<<gF, 256, 0, stream>>>(S0, out, Pb, Pa, Bq1h, Bq1l, Bq0h, Bq0l, 64);
    // state now in `out`; split(P128) now in Bq0.

    // ---- Phase 3: 15 sequential carry steps with P128 (in-place on out),
    //      NT=64 tiles -> 256 blocks = every CU busy ----
    for (int i = 1; i < 16; ++i)
        mfma_gemm<2, 64, 1, 0><<<gSeq, 256, 0, stream>>>(
            out, Bq0h, Bq0l, nullptr, out, out, 128, 128 * i);

    // ---- Phase 4: residual MLP stack (512-thr bf16 GEMMs); y in out, z->S0 ----
    for (int l = 0; l < NL; ++l) {
        mlp_gemm<<<gBig, 512, 0, stream>>>(
            out, BmH[l], mlpb + (size_t)l * Dd, S0, psum, psq);
        bn_stats<<<4, 256, 0, stream>>>(psum, psq, bns + (size_t)l * Dd,
                                        bnb + (size_t)l * Dd, abuf, cbuf);
        residual_gelu<<<2048, 256, 0, stream>>>(S0, out, out, abuf, cbuf);
    }
}